// Round 1
// baseline (481.525 us; speedup 1.0000x reference)
//
#include <hip/hip_runtime.h>

typedef unsigned short u16;
typedef unsigned int u32;
typedef __attribute__((ext_vector_type(8))) short bf16x8;
typedef __attribute__((ext_vector_type(4))) float f32x4;

#define MFMA_BF16(a, b, c) __builtin_amdgcn_mfma_f32_16x16x32_bf16((a), (b), (c), 0, 0, 0)

__device__ __forceinline__ u16 f2bf(float f) {
    u32 u = __builtin_bit_cast(u32, f);
    u32 r = u + 0x7FFFu + ((u >> 16) & 1u);   // round-to-nearest-even
    return (u16)(r >> 16);
}

__device__ __forceinline__ void gld16(const void* g, void* s) {
    __builtin_amdgcn_global_load_lds(
        (const __attribute__((address_space(1))) unsigned int*)g,
        (__attribute__((address_space(3))) unsigned int*)s, 16, 0, 0);
}

// ---------------- f32 -> bf16 convert (weights) ----------------
__global__ void cvt_k(const float* __restrict__ in, u16* __restrict__ out, int n4) {
    int i = blockIdx.x * blockDim.x + threadIdx.x;
    if (i >= n4) return;
    float4 v = ((const float4*)in)[i];
    ushort4 o;
    o.x = f2bf(v.x); o.y = f2bf(v.y); o.z = f2bf(v.z); o.w = f2bf(v.w);
    ((ushort4*)out)[i] = o;
}

// ---------------- LayerNorm (1024 cols) -> bf16 ----------------
__global__ __launch_bounds__(256) void ln_k(const float* __restrict__ x,
                                            u16* __restrict__ out,
                                            const float* __restrict__ sc,
                                            const float* __restrict__ bi) {
    const int row = blockIdx.x;
    const int tid = threadIdx.x;
    const float4 v = ((const float4*)(x + (size_t)row * 1024))[tid];
    float s  = v.x + v.y + v.z + v.w;
    float s2 = v.x*v.x + v.y*v.y + v.z*v.z + v.w*v.w;
    #pragma unroll
    for (int m = 32; m; m >>= 1) { s += __shfl_xor(s, m); s2 += __shfl_xor(s2, m); }
    __shared__ float red[8];
    const int w = tid >> 6, l = tid & 63;
    if (l == 0) { red[w] = s; red[4 + w] = s2; }
    __syncthreads();
    s  = red[0] + red[1] + red[2] + red[3];
    s2 = red[4] + red[5] + red[6] + red[7];
    const float mu  = s * (1.0f / 1024.0f);
    const float var = s2 * (1.0f / 1024.0f) - mu * mu;
    const float rs  = rsqrtf(var + 1e-5f);
    const float4 sv = ((const float4*)sc)[tid];
    const float4 bv = ((const float4*)bi)[tid];
    ushort4 o;
    o.x = f2bf((v.x - mu) * rs * sv.x + bv.x);
    o.y = f2bf((v.y - mu) * rs * sv.y + bv.y);
    o.z = f2bf((v.z - mu) * rs * sv.z + bv.z);
    o.w = f2bf((v.w - mu) * rs * sv.w + bv.w);
    ((ushort4*)(out + (size_t)row * 1024))[tid] = o;
}

// ---------------- GEMM: C[M,N] = A[M,K] @ B[N,K]^T  (both bf16, row-major) ----
// epi: 0 -> store bf16 to Cb
//      1 -> store f32  to Cf, += resid
//      2 -> exact gelu, store bf16 to Cb
__global__ __launch_bounds__(256) void gemm_bt_k(const u16* __restrict__ A,
                                                 const u16* __restrict__ B,
                                                 u16* __restrict__ Cb,
                                                 float* __restrict__ Cf,
                                                 const float* __restrict__ resid,
                                                 int M, int N, int K, int epi) {
    const int tid = threadIdx.x;
    const int w = tid >> 6, l = tid & 63, g = l >> 4, lc = l & 15;
    const int wr = w >> 1, wc = w & 1;
    const int row0 = blockIdx.y * 128, col0 = blockIdx.x * 128;

    __shared__ u16 As[128 * 32];
    __shared__ u16 Bs[128 * 32];

    f32x4 acc[4][4] = {};

    const int sr = tid >> 2, sq = tid & 3;
    const u16* ga = A + (size_t)(row0 + sr) * K + sq * 8;
    const u16* gb = B + (size_t)(col0 + sr) * K + sq * 8;
    const int nk = K >> 5;

    for (int kt = 0; kt < nk; ++kt) {
        __syncthreads();
        gld16(ga,                 (char*)As + tid * 16);
        gld16(ga + (size_t)64 * K, (char*)As + tid * 16 + 4096);
        gld16(gb,                 (char*)Bs + tid * 16);
        gld16(gb + (size_t)64 * K, (char*)Bs + tid * 16 + 4096);
        ga += 32; gb += 32;
        __syncthreads();

        bf16x8 af[4], bfr[4];
        #pragma unroll
        for (int i = 0; i < 4; ++i)
            af[i] = *(const bf16x8*)&As[(wr * 64 + i * 16 + lc) * 32 + g * 8];
        #pragma unroll
        for (int j = 0; j < 4; ++j)
            bfr[j] = *(const bf16x8*)&Bs[(wc * 64 + j * 16 + lc) * 32 + g * 8];
        #pragma unroll
        for (int i = 0; i < 4; ++i)
            #pragma unroll
            for (int j = 0; j < 4; ++j)
                acc[i][j] = MFMA_BF16(af[i], bfr[j], acc[i][j]);
    }

    #pragma unroll
    for (int i = 0; i < 4; ++i)
        #pragma unroll
        for (int j = 0; j < 4; ++j)
            #pragma unroll
            for (int r = 0; r < 4; ++r) {
                const int row = row0 + wr * 64 + i * 16 + g * 4 + r;
                const int col = col0 + wc * 64 + j * 16 + lc;
                const size_t off = (size_t)row * N + col;
                const float v = acc[i][j][r];
                if (epi == 0) {
                    Cb[off] = f2bf(v);
                } else if (epi == 1) {
                    Cf[off] = v + resid[off];
                } else {
                    const float gv = 0.5f * v * (1.0f + erff(v * 0.70710678118f));
                    Cb[off] = f2bf(gv);
                }
            }
}

// ---------------- Flash attention: B=2, H=16, S=2048, D=64 -------------------
// qkv: [4096 tokens][3072] bf16 (q|k|v each [16 heads][64])
// ctx: [4096 tokens][1024] bf16
__global__ __launch_bounds__(256) void attn_k(const u16* __restrict__ qkv,
                                              u16* __restrict__ ctx) {
    const int qt = blockIdx.x;          // 0..31  (q tile of 64 rows)
    const int bh = blockIdx.y;          // 0..31
    const int b = bh >> 4, h = bh & 15;
    const int tid = threadIdx.x, w = tid >> 6, l = tid & 63, g = l >> 4, lc = l & 15;
    const size_t tok0 = (size_t)b * 2048;

    const u16* Qg = qkv + (tok0 + qt * 64) * 3072 + h * 64;
    const u16* Kg = qkv + tok0 * 3072 + 1024 + h * 64;
    const u16* Vg = qkv + tok0 * 3072 + 2048 + h * 64;

    __shared__ u16 Qs[64 * 64];
    __shared__ u16 Ks[64 * 64];
    __shared__ u16 Vts[64 * 64];        // V transposed: [d][key]
    __shared__ u16 Ps[4][16 * 64];      // per-wave P strip

    // stage Q tile (64x64)
    {
        int idx = tid;
        gld16(Qg + (size_t)(idx >> 3) * 3072 + (idx & 7) * 8, (char*)Qs + idx * 16);
        idx += 256;
        gld16(Qg + (size_t)(idx >> 3) * 3072 + (idx & 7) * 8, (char*)Qs + idx * 16);
    }
    __syncthreads();
    bf16x8 qf[2];
    qf[0] = *(const bf16x8*)&Qs[(w * 16 + lc) * 64 + g * 8];
    qf[1] = *(const bf16x8*)&Qs[(w * 16 + lc) * 64 + 32 + g * 8];

    f32x4 oacc[4] = {};
    float mrow[4], lrow[4];
    #pragma unroll
    for (int r = 0; r < 4; ++r) { mrow[r] = -1e30f; lrow[r] = 0.0f; }

    for (int kt = 0; kt < 32; ++kt) {
        __syncthreads();
        // stage K tile
        {
            int idx = tid;
            gld16(Kg + (size_t)(kt * 64 + (idx >> 3)) * 3072 + (idx & 7) * 8,
                  (char*)Ks + idx * 16);
            idx += 256;
            gld16(Kg + (size_t)(kt * 64 + (idx >> 3)) * 3072 + (idx & 7) * 8,
                  (char*)Ks + idx * 16);
        }
        // stage V transposed
        #pragma unroll
        for (int p = 0; p < 2; ++p) {
            const int idx = p * 256 + tid;
            const int key = idx >> 3, c = idx & 7;
            const uint4 raw = *(const uint4*)(Vg + (size_t)(kt * 64 + key) * 3072 + c * 8);
            const u32 vv[4] = {raw.x, raw.y, raw.z, raw.w};
            #pragma unroll
            for (int jj = 0; jj < 4; ++jj) {
                Vts[(c * 8 + 2 * jj)     * 64 + key] = (u16)(vv[jj] & 0xFFFFu);
                Vts[(c * 8 + 2 * jj + 1) * 64 + key] = (u16)(vv[jj] >> 16);
            }
        }
        __syncthreads();

        // S strip (16 x 64) = Q_strip @ K^T
        f32x4 sacc[4] = {};
        #pragma unroll
        for (int kk = 0; kk < 2; ++kk)
            #pragma unroll
            for (int nt = 0; nt < 4; ++nt) {
                const bf16x8 kb = *(const bf16x8*)&Ks[(nt * 16 + lc) * 64 + kk * 32 + g * 8];
                sacc[nt] = MFMA_BF16(qf[kk], kb, sacc[nt]);
            }

        // online softmax on the strip
        float p[4][4];
        #pragma unroll
        for (int r = 0; r < 4; ++r) {
            float mx = -1e30f;
            #pragma unroll
            for (int nt = 0; nt < 4; ++nt) {
                sacc[nt][r] *= 0.125f;
                mx = fmaxf(mx, sacc[nt][r]);
            }
            #pragma unroll
            for (int mm = 1; mm < 16; mm <<= 1) mx = fmaxf(mx, __shfl_xor(mx, mm));
            const float mnew = fmaxf(mrow[r], mx);
            const float corr = __expf(mrow[r] - mnew);
            float ps = 0.0f;
            #pragma unroll
            for (int nt = 0; nt < 4; ++nt) {
                const float pv = __expf(sacc[nt][r] - mnew);
                p[nt][r] = pv;
                ps += pv;
            }
            #pragma unroll
            for (int mm = 1; mm < 16; mm <<= 1) ps += __shfl_xor(ps, mm);
            lrow[r] = lrow[r] * corr + ps;
            mrow[r] = mnew;
            #pragma unroll
            for (int nt = 0; nt < 4; ++nt) oacc[nt][r] *= corr;
        }

        // write P strip to LDS (A-fragment layout source)
        #pragma unroll
        for (int nt = 0; nt < 4; ++nt)
            #pragma unroll
            for (int r = 0; r < 4; ++r)
                Ps[w][(g * 4 + r) * 64 + nt * 16 + lc] = f2bf(p[nt][r]);

        // O += P @ V   (DS ops are in-order within a wave)
        #pragma unroll
        for (int kk = 0; kk < 2; ++kk) {
            const bf16x8 pa = *(const bf16x8*)&Ps[w][lc * 64 + kk * 32 + g * 8];
            #pragma unroll
            for (int nt = 0; nt < 4; ++nt) {
                const bf16x8 vb = *(const bf16x8*)&Vts[(nt * 16 + lc) * 64 + kk * 32 + g * 8];
                oacc[nt] = MFMA_BF16(pa, vb, oacc[nt]);
            }
        }
    }

    // epilogue: normalize, store
    #pragma unroll
    for (int nt = 0; nt < 4; ++nt)
        #pragma unroll
        for (int r = 0; r < 4; ++r) {
            const float o = oacc[nt][r] / lrow[r];
            const size_t token = tok0 + qt * 64 + w * 16 + g * 4 + r;
            ctx[token * 1024 + h * 64 + nt * 16 + lc] = f2bf(o);
        }
}

// -----------------------------------------------------------------------------
extern "C" void kernel_launch(void* const* d_in, const int* in_sizes, int n_in,
                              void* d_out, int out_size, void* d_ws, size_t ws_size,
                              hipStream_t stream) {
    const float* x      = (const float*)d_in[0];
    const float* qkv_w  = (const float*)d_in[1];
    const float* out_w  = (const float*)d_in[2];
    const float* up_w   = (const float*)d_in[3];
    const float* down_w = (const float*)d_in[4];
    const float* n1s    = (const float*)d_in[5];
    const float* n1b    = (const float*)d_in[6];
    const float* n2s    = (const float*)d_in[7];
    const float* n2b    = (const float*)d_in[8];
    float* out = (float*)d_out;

    char* ws = (char*)d_ws;
    size_t off = 0;
    auto alloc = [&](size_t bytes) -> void* {
        void* p = ws + off;
        off += (bytes + 255) & ~(size_t)255;
        return p;
    };
    u16*   qkvw_b = (u16*)alloc(3072ull * 1024 * 2);
    u16*   outw_b = (u16*)alloc(1024ull * 1024 * 2);
    u16*   upw_b  = (u16*)alloc(4096ull * 1024 * 2);
    u16*   dnw_b  = (u16*)alloc(1024ull * 4096 * 2);
    u16*   h_b    = (u16*)alloc(4096ull * 1024 * 2);
    u16*   qkv_o  = (u16*)alloc(4096ull * 3072 * 2);
    u16*   ctx    = (u16*)alloc(4096ull * 1024 * 2);
    float* x2     = (float*)alloc(4096ull * 1024 * 4);
    u16*   u      = (u16*)alloc(4096ull * 4096 * 2);

    // weight conversions
    cvt_k<<<(3072 * 1024 / 4 + 255) / 256, 256, 0, stream>>>(qkv_w,  qkvw_b, 3072 * 1024 / 4);
    cvt_k<<<(1024 * 1024 / 4 + 255) / 256, 256, 0, stream>>>(out_w,  outw_b, 1024 * 1024 / 4);
    cvt_k<<<(4096 * 1024 / 4 + 255) / 256, 256, 0, stream>>>(up_w,   upw_b,  4096 * 1024 / 4);
    cvt_k<<<(1024 * 4096 / 4 + 255) / 256, 256, 0, stream>>>(down_w, dnw_b,  1024 * 4096 / 4);

    // --- attention sublayer ---
    ln_k<<<4096, 256, 0, stream>>>(x, h_b, n1s, n1b);
    gemm_bt_k<<<dim3(24, 32), 256, 0, stream>>>(h_b, qkvw_b, qkv_o, nullptr, nullptr,
                                                4096, 3072, 1024, 0);
    attn_k<<<dim3(32, 32), 256, 0, stream>>>(qkv_o, ctx);
    gemm_bt_k<<<dim3(8, 32), 256, 0, stream>>>(ctx, outw_b, nullptr, x2, x,
                                               4096, 1024, 1024, 1);

    // --- FFN sublayer ---
    ln_k<<<4096, 256, 0, stream>>>(x2, h_b, n2s, n2b);
    gemm_bt_k<<<dim3(32, 32), 256, 0, stream>>>(h_b, upw_b, u, nullptr, nullptr,
                                                4096, 4096, 1024, 2);
    gemm_bt_k<<<dim3(8, 32), 256, 0, stream>>>(u, dnw_b, nullptr, out, x2,
                                               4096, 1024, 4096, 1);
}

// Round 2
// 428.394 us; speedup vs baseline: 1.1240x; 1.1240x over previous
//
#include <hip/hip_runtime.h>

typedef unsigned short u16;
typedef unsigned int u32;
typedef __attribute__((ext_vector_type(8))) short bf16x8;
typedef __attribute__((ext_vector_type(4))) float f32x4;

#define MFMA_BF16(a, b, c) __builtin_amdgcn_mfma_f32_16x16x32_bf16((a), (b), (c), 0, 0, 0)

__device__ __forceinline__ u16 f2bf(float f) {
    u32 u = __builtin_bit_cast(u32, f);
    u32 r = u + 0x7FFFu + ((u >> 16) & 1u);   // round-to-nearest-even
    return (u16)(r >> 16);
}

__device__ __forceinline__ void gld16(const void* g, void* s) {
    __builtin_amdgcn_global_load_lds(
        (const __attribute__((address_space(1))) unsigned int*)g,
        (__attribute__((address_space(3))) unsigned int*)s, 16, 0, 0);
}

// ---------------- f32 -> bf16 convert (weights) ----------------
__global__ void cvt_k(const float* __restrict__ in, u16* __restrict__ out, int n4) {
    int i = blockIdx.x * blockDim.x + threadIdx.x;
    if (i >= n4) return;
    float4 v = ((const float4*)in)[i];
    ushort4 o;
    o.x = f2bf(v.x); o.y = f2bf(v.y); o.z = f2bf(v.z); o.w = f2bf(v.w);
    ((ushort4*)out)[i] = o;
}

// ---------------- LayerNorm (1024 cols) -> bf16 ----------------
__global__ __launch_bounds__(256) void ln_k(const float* __restrict__ x,
                                            u16* __restrict__ out,
                                            const float* __restrict__ sc,
                                            const float* __restrict__ bi) {
    const int row = blockIdx.x;
    const int tid = threadIdx.x;
    const float4 v = ((const float4*)(x + (size_t)row * 1024))[tid];
    float s  = v.x + v.y + v.z + v.w;
    float s2 = v.x*v.x + v.y*v.y + v.z*v.z + v.w*v.w;
    #pragma unroll
    for (int m = 32; m; m >>= 1) { s += __shfl_xor(s, m); s2 += __shfl_xor(s2, m); }
    __shared__ float red[8];
    const int w = tid >> 6, l = tid & 63;
    if (l == 0) { red[w] = s; red[4 + w] = s2; }
    __syncthreads();
    s  = red[0] + red[1] + red[2] + red[3];
    s2 = red[4] + red[5] + red[6] + red[7];
    const float mu  = s * (1.0f / 1024.0f);
    const float var = s2 * (1.0f / 1024.0f) - mu * mu;
    const float rs  = rsqrtf(var + 1e-5f);
    const float4 sv = ((const float4*)sc)[tid];
    const float4 bv = ((const float4*)bi)[tid];
    ushort4 o;
    o.x = f2bf((v.x - mu) * rs * sv.x + bv.x);
    o.y = f2bf((v.y - mu) * rs * sv.y + bv.y);
    o.z = f2bf((v.z - mu) * rs * sv.z + bv.z);
    o.w = f2bf((v.w - mu) * rs * sv.w + bv.w);
    ((ushort4*)(out + (size_t)row * 1024))[tid] = o;
}

// ---------------- GEMM: C[M,N] = A[M,K] @ B[N,K]^T  (both bf16, row-major) ----
__global__ __launch_bounds__(256) void gemm_bt_k(const u16* __restrict__ A,
                                                 const u16* __restrict__ B,
                                                 u16* __restrict__ Cb,
                                                 float* __restrict__ Cf,
                                                 const float* __restrict__ resid,
                                                 int M, int N, int K, int epi) {
    const int tid = threadIdx.x;
    const int w = tid >> 6, l = tid & 63, g = l >> 4, lc = l & 15;
    const int wr = w >> 1, wc = w & 1;
    const int row0 = blockIdx.y * 128, col0 = blockIdx.x * 128;

    __shared__ u16 As[128 * 32];
    __shared__ u16 Bs[128 * 32];

    f32x4 acc[4][4] = {};

    const int sr = tid >> 2, sq = tid & 3;
    const u16* ga = A + (size_t)(row0 + sr) * K + sq * 8;
    const u16* gb = B + (size_t)(col0 + sr) * K + sq * 8;
    const int nk = K >> 5;

    for (int kt = 0; kt < nk; ++kt) {
        __syncthreads();
        gld16(ga,                 (char*)As + tid * 16);
        gld16(ga + (size_t)64 * K, (char*)As + tid * 16 + 4096);
        gld16(gb,                 (char*)Bs + tid * 16);
        gld16(gb + (size_t)64 * K, (char*)Bs + tid * 16 + 4096);
        ga += 32; gb += 32;
        __syncthreads();

        bf16x8 af[4], bfr[4];
        #pragma unroll
        for (int i = 0; i < 4; ++i)
            af[i] = *(const bf16x8*)&As[(wr * 64 + i * 16 + lc) * 32 + g * 8];
        #pragma unroll
        for (int j = 0; j < 4; ++j)
            bfr[j] = *(const bf16x8*)&Bs[(wc * 64 + j * 16 + lc) * 32 + g * 8];
        #pragma unroll
        for (int i = 0; i < 4; ++i)
            #pragma unroll
            for (int j = 0; j < 4; ++j)
                acc[i][j] = MFMA_BF16(af[i], bfr[j], acc[i][j]);
    }

    #pragma unroll
    for (int i = 0; i < 4; ++i)
        #pragma unroll
        for (int j = 0; j < 4; ++j)
            #pragma unroll
            for (int r = 0; r < 4; ++r) {
                const int row = row0 + wr * 64 + i * 16 + g * 4 + r;
                const int col = col0 + wc * 64 + j * 16 + lc;
                const size_t off = (size_t)row * N + col;
                const float v = acc[i][j][r];
                if (epi == 0) {
                    Cb[off] = f2bf(v);
                } else if (epi == 1) {
                    Cf[off] = v + resid[off];
                } else {
                    const float gv = 0.5f * v * (1.0f + erff(v * 0.70710678118f));
                    Cb[off] = f2bf(gv);
                }
            }
}

// ---------------- Flash attention: B=2, H=16, S=2048, D=64 -------------------
// All LDS tiles are 64 rows x 64 bf16 cols (128 B rows). XOR swizzles:
//   K/Q : stored octet = orig_octet ^ (row & 7)
//   V   : stored octet = orig_octet ^ (((row>>3) & 3) << 1)   (row = key)
//   P   : stored octet = orig_octet ^ ((row ^ (row>>3)) & 7)  (row = local q)
// Staging uses global_load_lds with LINEAR LDS dest + pre-swizzled global src.
__global__ __launch_bounds__(256) void attn_k(const u16* __restrict__ qkv,
                                              u16* __restrict__ ctx) {
    const int qt = blockIdx.x;          // 0..31  (q tile of 64 rows)
    const int bh = blockIdx.y;          // 0..31
    const int b = bh >> 4, h = bh & 15;
    const int tid = threadIdx.x, w = tid >> 6, l = tid & 63, g = l >> 4, lc = l & 15;
    const size_t tok0 = (size_t)b * 2048;

    const u16* Qg = qkv + (tok0 + qt * 64) * 3072 + h * 64;
    const u16* Kg = qkv + tok0 * 3072 + 1024 + h * 64;
    const u16* Vg = qkv + tok0 * 3072 + 2048 + h * 64;

    __shared__ u16 Ks[64 * 64];
    __shared__ u16 Vs[64 * 64];
    __shared__ u16 QPs[64 * 64];        // Q tile in prologue, then P strips (1024 u16/wave)
    u16* Pw = QPs + w * 1024;

    // stage Q tile (swizzled source, linear dest)
    {
        int s = tid;
        int row = s >> 3, c = (s & 7) ^ (row & 7);
        gld16(Qg + (size_t)row * 3072 + c * 8, (char*)QPs + s * 16);
        s = tid + 256;
        row = s >> 3; c = (s & 7) ^ (row & 7);
        gld16(Qg + (size_t)row * 3072 + c * 8, (char*)QPs + s * 16);
    }
    __syncthreads();
    bf16x8 qf[2];
    {
        const int qrow = w * 16 + lc;
        qf[0] = *(const bf16x8*)&QPs[qrow * 64 + ((g        ^ (lc & 7)) * 8)];
        qf[1] = *(const bf16x8*)&QPs[qrow * 64 + (((4 + g)  ^ (lc & 7)) * 8)];
    }

    f32x4 oacc[4] = {};
    float mrow[4], lrow[4];
    #pragma unroll
    for (int r = 0; r < 4; ++r) { mrow[r] = -1e30f; lrow[r] = 0.0f; }

    const float scl = 0.125f * 1.44269504f;   // /sqrt(64) * log2(e): softmax in 2^x domain
    const int swzl = (lc ^ (lc >> 3)) & 7;    // P-read row swizzle for this lane

    for (int kt = 0; kt < 32; ++kt) {
        __syncthreads();
        // stage K + V tiles (swizzled source, linear dest)
        {
            int s = tid;
            int row = s >> 3;
            int ck = (s & 7) ^ (row & 7);
            int cv = (s & 7) ^ (((row >> 3) & 3) << 1);
            gld16(Kg + (size_t)(kt * 64 + row) * 3072 + ck * 8, (char*)Ks + s * 16);
            gld16(Vg + (size_t)(kt * 64 + row) * 3072 + cv * 8, (char*)Vs + s * 16);
            s = tid + 256;
            row = s >> 3;
            ck = (s & 7) ^ (row & 7);
            cv = (s & 7) ^ (((row >> 3) & 3) << 1);
            gld16(Kg + (size_t)(kt * 64 + row) * 3072 + ck * 8, (char*)Ks + s * 16);
            gld16(Vg + (size_t)(kt * 64 + row) * 3072 + cv * 8, (char*)Vs + s * 16);
        }
        __syncthreads();

        // S strip (16 x 64) = Q_strip @ K^T  (swizzled K reads: conflict-free)
        f32x4 sacc[4] = {};
        #pragma unroll
        for (int kk = 0; kk < 2; ++kk)
            #pragma unroll
            for (int nt = 0; nt < 4; ++nt) {
                const int krow = nt * 16 + lc;
                const bf16x8 kb = *(const bf16x8*)
                    &Ks[krow * 64 + (((kk * 4 + g) ^ (lc & 7)) * 8)];
                sacc[nt] = MFMA_BF16(qf[kk], kb, sacc[nt]);
            }

        // online softmax on the strip (log2 domain)
        float p[4][4];
        #pragma unroll
        for (int r = 0; r < 4; ++r) {
            float mx = -1e30f;
            #pragma unroll
            for (int nt = 0; nt < 4; ++nt) {
                sacc[nt][r] *= scl;
                mx = fmaxf(mx, sacc[nt][r]);
            }
            #pragma unroll
            for (int mm = 1; mm < 16; mm <<= 1) mx = fmaxf(mx, __shfl_xor(mx, mm));
            const float mnew = fmaxf(mrow[r], mx);
            const float corr = exp2f(mrow[r] - mnew);
            float ps = 0.0f;
            #pragma unroll
            for (int nt = 0; nt < 4; ++nt) {
                const float pv = exp2f(sacc[nt][r] - mnew);
                p[nt][r] = pv;
                ps += pv;
            }
            #pragma unroll
            for (int mm = 1; mm < 16; mm <<= 1) ps += __shfl_xor(ps, mm);
            lrow[r] = lrow[r] * corr + ps;
            mrow[r] = mnew;
            #pragma unroll
            for (int nt = 0; nt < 4; ++nt) oacc[nt][r] *= corr;
        }

        // write P strip to LDS (row-swizzled octets)
        #pragma unroll
        for (int r = 0; r < 4; ++r) {
            const int prow = g * 4 + r;
            const int swzr = (prow ^ (prow >> 3)) & 7;
            #pragma unroll
            for (int nt = 0; nt < 4; ++nt)
                Pw[prow * 64 + (((nt * 2 + (lc >> 3)) ^ swzr) * 8) + (lc & 7)]
                    = f2bf(p[nt][r]);
        }

        // O += P @ V   (P: swizzled b128 reads; V: scalar reads from row-major Vs)
        #pragma unroll
        for (int kk = 0; kk < 2; ++kk) {
            const bf16x8 pa = *(const bf16x8*)
                &Pw[lc * 64 + (((kk * 4 + g) ^ swzl) * 8)];
            #pragma unroll
            for (int nt = 0; nt < 4; ++nt) {
                bf16x8 vb;
                #pragma unroll
                for (int j = 0; j < 8; ++j)
                    vb[j] = (short)Vs[(kk * 32 + g * 8 + j) * 64 + ((nt ^ g) * 16) + lc];
                oacc[nt] = MFMA_BF16(pa, vb, oacc[nt]);
            }
        }
    }

    // epilogue: normalize, store
    #pragma unroll
    for (int nt = 0; nt < 4; ++nt)
        #pragma unroll
        for (int r = 0; r < 4; ++r) {
            const float o = oacc[nt][r] / lrow[r];
            const size_t token = tok0 + qt * 64 + w * 16 + g * 4 + r;
            ctx[token * 1024 + h * 64 + nt * 16 + lc] = f2bf(o);
        }
}

// -----------------------------------------------------------------------------
extern "C" void kernel_launch(void* const* d_in, const int* in_sizes, int n_in,
                              void* d_out, int out_size, void* d_ws, size_t ws_size,
                              hipStream_t stream) {
    const float* x      = (const float*)d_in[0];
    const float* qkv_w  = (const float*)d_in[1];
    const float* out_w  = (const float*)d_in[2];
    const float* up_w   = (const float*)d_in[3];
    const float* down_w = (const float*)d_in[4];
    const float* n1s    = (const float*)d_in[5];
    const float* n1b    = (const float*)d_in[6];
    const float* n2s    = (const float*)d_in[7];
    const float* n2b    = (const float*)d_in[8];
    float* out = (float*)d_out;

    char* ws = (char*)d_ws;
    size_t off = 0;
    auto alloc = [&](size_t bytes) -> void* {
        void* p = ws + off;
        off += (bytes + 255) & ~(size_t)255;
        return p;
    };
    u16*   qkvw_b = (u16*)alloc(3072ull * 1024 * 2);
    u16*   outw_b = (u16*)alloc(1024ull * 1024 * 2);
    u16*   upw_b  = (u16*)alloc(4096ull * 1024 * 2);
    u16*   dnw_b  = (u16*)alloc(1024ull * 4096 * 2);
    u16*   h_b    = (u16*)alloc(4096ull * 1024 * 2);
    u16*   qkv_o  = (u16*)alloc(4096ull * 3072 * 2);
    u16*   ctx    = (u16*)alloc(4096ull * 1024 * 2);
    float* x2     = (float*)alloc(4096ull * 1024 * 4);
    u16*   u      = (u16*)alloc(4096ull * 4096 * 2);

    // weight conversions
    cvt_k<<<(3072 * 1024 / 4 + 255) / 256, 256, 0, stream>>>(qkv_w,  qkvw_b, 3072 * 1024 / 4);
    cvt_k<<<(1024 * 1024 / 4 + 255) / 256, 256, 0, stream>>>(out_w,  outw_b, 1024 * 1024 / 4);
    cvt_k<<<(4096 * 1024 / 4 + 255) / 256, 256, 0, stream>>>(up_w,   upw_b,  4096 * 1024 / 4);
    cvt_k<<<(1024 * 4096 / 4 + 255) / 256, 256, 0, stream>>>(down_w, dnw_b,  1024 * 4096 / 4);

    // --- attention sublayer ---
    ln_k<<<4096, 256, 0, stream>>>(x, h_b, n1s, n1b);
    gemm_bt_k<<<dim3(24, 32), 256, 0, stream>>>(h_b, qkvw_b, qkv_o, nullptr, nullptr,
                                                4096, 3072, 1024, 0);
    attn_k<<<dim3(32, 32), 256, 0, stream>>>(qkv_o, ctx);
    gemm_bt_k<<<dim3(8, 32), 256, 0, stream>>>(ctx, outw_b, nullptr, x2, x,
                                               4096, 1024, 1024, 1);

    // --- FFN sublayer ---
    ln_k<<<4096, 256, 0, stream>>>(x2, h_b, n2s, n2b);
    gemm_bt_k<<<dim3(32, 32), 256, 0, stream>>>(h_b, upw_b, u, nullptr, nullptr,
                                                4096, 4096, 1024, 2);
    gemm_bt_k<<<dim3(8, 32), 256, 0, stream>>>(u, dnw_b, nullptr, out, x2,
                                               4096, 1024, 4096, 1);
}

// Round 3
// 413.315 us; speedup vs baseline: 1.1650x; 1.0365x over previous
//
#include <hip/hip_runtime.h>

typedef unsigned short u16;
typedef unsigned int u32;
typedef __attribute__((ext_vector_type(8))) short bf16x8;
typedef __attribute__((ext_vector_type(4))) float f32x4;

#define MFMA_BF16(a, b, c) __builtin_amdgcn_mfma_f32_16x16x32_bf16((a), (b), (c), 0, 0, 0)

__device__ __forceinline__ u16 f2bf(float f) {
    u32 u = __builtin_bit_cast(u32, f);
    u32 r = u + 0x7FFFu + ((u >> 16) & 1u);   // round-to-nearest-even
    return (u16)(r >> 16);
}

__device__ __forceinline__ void gld16(const void* g, void* s) {
    __builtin_amdgcn_global_load_lds(
        (const __attribute__((address_space(1))) unsigned int*)g,
        (__attribute__((address_space(3))) unsigned int*)s, 16, 0, 0);
}

// ---------------- f32 -> bf16 convert (weights) ----------------
__global__ void cvt_k(const float* __restrict__ in, u16* __restrict__ out, int n4) {
    int i = blockIdx.x * blockDim.x + threadIdx.x;
    if (i >= n4) return;
    float4 v = ((const float4*)in)[i];
    ushort4 o;
    o.x = f2bf(v.x); o.y = f2bf(v.y); o.z = f2bf(v.z); o.w = f2bf(v.w);
    ((ushort4*)out)[i] = o;
}

// ---------------- LayerNorm (1024 cols) -> bf16 ----------------
__global__ __launch_bounds__(256) void ln_k(const float* __restrict__ x,
                                            u16* __restrict__ out,
                                            const float* __restrict__ sc,
                                            const float* __restrict__ bi) {
    const int row = blockIdx.x;
    const int tid = threadIdx.x;
    const float4 v = ((const float4*)(x + (size_t)row * 1024))[tid];
    float s  = v.x + v.y + v.z + v.w;
    float s2 = v.x*v.x + v.y*v.y + v.z*v.z + v.w*v.w;
    #pragma unroll
    for (int m = 32; m; m >>= 1) { s += __shfl_xor(s, m); s2 += __shfl_xor(s2, m); }
    __shared__ float red[8];
    const int w = tid >> 6, l = tid & 63;
    if (l == 0) { red[w] = s; red[4 + w] = s2; }
    __syncthreads();
    s  = red[0] + red[1] + red[2] + red[3];
    s2 = red[4] + red[5] + red[6] + red[7];
    const float mu  = s * (1.0f / 1024.0f);
    const float var = s2 * (1.0f / 1024.0f) - mu * mu;
    const float rs  = rsqrtf(var + 1e-5f);
    const float4 sv = ((const float4*)sc)[tid];
    const float4 bv = ((const float4*)bi)[tid];
    ushort4 o;
    o.x = f2bf((v.x - mu) * rs * sv.x + bv.x);
    o.y = f2bf((v.y - mu) * rs * sv.y + bv.y);
    o.z = f2bf((v.z - mu) * rs * sv.z + bv.z);
    o.w = f2bf((v.w - mu) * rs * sv.w + bv.w);
    ((ushort4*)(out + (size_t)row * 1024))[tid] = o;
}

// ---------------- GEMM: C[M,N] = A[M,K] @ B[N,K]^T  (both bf16, row-major) ----
__global__ __launch_bounds__(256) void gemm_bt_k(const u16* __restrict__ A,
                                                 const u16* __restrict__ B,
                                                 u16* __restrict__ Cb,
                                                 float* __restrict__ Cf,
                                                 const float* __restrict__ resid,
                                                 int M, int N, int K, int epi) {
    const int tid = threadIdx.x;
    const int w = tid >> 6, l = tid & 63, g = l >> 4, lc = l & 15;
    const int wr = w >> 1, wc = w & 1;
    const int row0 = blockIdx.y * 128, col0 = blockIdx.x * 128;

    __shared__ u16 As[128 * 32];
    __shared__ u16 Bs[128 * 32];

    f32x4 acc[4][4] = {};

    const int sr = tid >> 2, sq = tid & 3;
    const u16* ga = A + (size_t)(row0 + sr) * K + sq * 8;
    const u16* gb = B + (size_t)(col0 + sr) * K + sq * 8;
    const int nk = K >> 5;

    for (int kt = 0; kt < nk; ++kt) {
        __syncthreads();
        gld16(ga,                 (char*)As + tid * 16);
        gld16(ga + (size_t)64 * K, (char*)As + tid * 16 + 4096);
        gld16(gb,                 (char*)Bs + tid * 16);
        gld16(gb + (size_t)64 * K, (char*)Bs + tid * 16 + 4096);
        ga += 32; gb += 32;
        __syncthreads();

        bf16x8 af[4], bfr[4];
        #pragma unroll
        for (int i = 0; i < 4; ++i)
            af[i] = *(const bf16x8*)&As[(wr * 64 + i * 16 + lc) * 32 + g * 8];
        #pragma unroll
        for (int j = 0; j < 4; ++j)
            bfr[j] = *(const bf16x8*)&Bs[(wc * 64 + j * 16 + lc) * 32 + g * 8];
        #pragma unroll
        for (int i = 0; i < 4; ++i)
            #pragma unroll
            for (int j = 0; j < 4; ++j)
                acc[i][j] = MFMA_BF16(af[i], bfr[j], acc[i][j]);
    }

    #pragma unroll
    for (int i = 0; i < 4; ++i)
        #pragma unroll
        for (int j = 0; j < 4; ++j)
            #pragma unroll
            for (int r = 0; r < 4; ++r) {
                const int row = row0 + wr * 64 + i * 16 + g * 4 + r;
                const int col = col0 + wc * 64 + j * 16 + lc;
                const size_t off = (size_t)row * N + col;
                const float v = acc[i][j][r];
                if (epi == 0) {
                    Cb[off] = f2bf(v);
                } else if (epi == 1) {
                    Cf[off] = v + resid[off];
                } else {
                    const float gv = 0.5f * v * (1.0f + erff(v * 0.70710678118f));
                    Cb[off] = f2bf(gv);
                }
            }
}

// ---------------- V transpose: qkv V-part [token][h*64+d] -> vt[bh][d][token] --
__global__ __launch_bounds__(256) void tr_v_k(const u16* __restrict__ qkv,
                                              u16* __restrict__ vt) {
    const int tt = blockIdx.x;          // token tile 0..31
    const int bh = blockIdx.y;          // 0..31
    const int b = bh >> 4, h = bh & 15;
    const u16* src = qkv + (size_t)(b * 2048 + tt * 64) * 3072 + 2048 + h * 64;
    u16* dst = vt + (size_t)bh * 64 * 2048 + tt * 64;

    __shared__ u16 T[64 * 64];          // swizzled: V[row][d] at row*64 + ((d>>3)^(row&7))*8 + (d&7)

    #pragma unroll
    for (int it = 0; it < 2; ++it) {
        const int idx = it * 256 + threadIdx.x;
        const int trow = idx >> 3, oct = idx & 7;
        const uint4 v = *(const uint4*)(src + (size_t)trow * 3072 + oct * 8);
        *(uint4*)&T[trow * 64 + ((oct ^ (trow & 7)) * 8)] = v;
    }
    __syncthreads();
    #pragma unroll
    for (int it = 0; it < 2; ++it) {
        const int idx = it * 256 + threadIdx.x;
        const int d = idx >> 3, t8 = idx & 7;
        ushort vals[8];
        #pragma unroll
        for (int j = 0; j < 8; ++j) {
            const int row = t8 * 8 + j;
            vals[j] = T[row * 64 + (((d >> 3) ^ (row & 7)) * 8) + (d & 7)];
        }
        *(uint4*)(dst + (size_t)d * 2048 + t8 * 8) = *(const uint4*)vals;
    }
}

// ---------------- Flash attention: B=2, H=16, S=2048, D=64 -------------------
// K and V^T tiles both staged as [16-row-groups of 64 cols], octet swizzle
// stored_octet = orig_octet ^ (row & 7); linear LDS dest + pre-swizzled src.
__global__ __launch_bounds__(256) void attn_k(const u16* __restrict__ qkv,
                                              const u16* __restrict__ vt,
                                              u16* __restrict__ ctx) {
    const int qt = blockIdx.x;          // 0..31  (q tile of 64 rows)
    const int bh = blockIdx.y;          // 0..31
    const int b = bh >> 4, h = bh & 15;
    const int tid = threadIdx.x, w = tid >> 6, l = tid & 63, g = l >> 4, lc = l & 15;
    const size_t tok0 = (size_t)b * 2048;

    const u16* Qg  = qkv + (tok0 + qt * 64) * 3072 + h * 64;
    const u16* Kg  = qkv + tok0 * 3072 + 1024 + h * 64;
    const u16* Vtg = vt + (size_t)bh * 64 * 2048;      // [d][token-in-batch]

    __shared__ u16 Ks[64 * 64];
    __shared__ u16 Vts[64 * 64];        // [d][key] swizzled like Ks
    __shared__ u16 QPs[64 * 64];        // Q tile in prologue, then P strips (1024 u16/wave)
    u16* Pw = QPs + w * 1024;

    // stage Q tile (swizzled source, linear dest)
    {
        int s = tid;
        int row = s >> 3, c = (s & 7) ^ (row & 7);
        gld16(Qg + (size_t)row * 3072 + c * 8, (char*)QPs + s * 16);
        s = tid + 256;
        row = s >> 3; c = (s & 7) ^ (row & 7);
        gld16(Qg + (size_t)row * 3072 + c * 8, (char*)QPs + s * 16);
    }
    __syncthreads();
    bf16x8 qf[2];
    {
        const int qrow = w * 16 + lc;
        qf[0] = *(const bf16x8*)&QPs[qrow * 64 + ((g       ^ (lc & 7)) * 8)];
        qf[1] = *(const bf16x8*)&QPs[qrow * 64 + (((4 + g) ^ (lc & 7)) * 8)];
    }

    f32x4 oacc[4] = {};
    float mrow[4], lrow[4];
    #pragma unroll
    for (int r = 0; r < 4; ++r) { mrow[r] = -1e30f; lrow[r] = 0.0f; }

    const float scl = 0.125f * 1.44269504f;   // /sqrt(64) * log2(e): softmax in 2^x domain
    const int swzl = (lc ^ (lc >> 3)) & 7;    // P-read row swizzle for this lane

    for (int kt = 0; kt < 32; ++kt) {
        __syncthreads();
        // stage K + V^T tiles (swizzled source, linear dest)
        {
            int s = tid;
            int row = s >> 3;
            int c = (s & 7) ^ (row & 7);
            gld16(Kg  + (size_t)(kt * 64 + row) * 3072 + c * 8, (char*)Ks + s * 16);
            gld16(Vtg + (size_t)row * 2048 + kt * 64 + c * 8,   (char*)Vts + s * 16);
            s = tid + 256;
            row = s >> 3;
            c = (s & 7) ^ (row & 7);
            gld16(Kg  + (size_t)(kt * 64 + row) * 3072 + c * 8, (char*)Ks + s * 16);
            gld16(Vtg + (size_t)row * 2048 + kt * 64 + c * 8,   (char*)Vts + s * 16);
        }
        __syncthreads();

        // S strip (16 x 64) = Q_strip @ K^T  (swizzled K reads: conflict-free)
        f32x4 sacc[4] = {};
        #pragma unroll
        for (int kk = 0; kk < 2; ++kk)
            #pragma unroll
            for (int nt = 0; nt < 4; ++nt) {
                const int krow = nt * 16 + lc;
                const bf16x8 kb = *(const bf16x8*)
                    &Ks[krow * 64 + (((kk * 4 + g) ^ (lc & 7)) * 8)];
                sacc[nt] = MFMA_BF16(qf[kk], kb, sacc[nt]);
            }

        // online softmax on the strip (log2 domain)
        float p[4][4];
        #pragma unroll
        for (int r = 0; r < 4; ++r) {
            float mx = -1e30f;
            #pragma unroll
            for (int nt = 0; nt < 4; ++nt) {
                sacc[nt][r] *= scl;
                mx = fmaxf(mx, sacc[nt][r]);
            }
            #pragma unroll
            for (int mm = 1; mm < 16; mm <<= 1) mx = fmaxf(mx, __shfl_xor(mx, mm));
            const float mnew = fmaxf(mrow[r], mx);
            const float corr = exp2f(mrow[r] - mnew);
            float ps = 0.0f;
            #pragma unroll
            for (int nt = 0; nt < 4; ++nt) {
                const float pv = exp2f(sacc[nt][r] - mnew);
                p[nt][r] = pv;
                ps += pv;
            }
            #pragma unroll
            for (int mm = 1; mm < 16; mm <<= 1) ps += __shfl_xor(ps, mm);
            lrow[r] = lrow[r] * corr + ps;
            mrow[r] = mnew;
            #pragma unroll
            for (int nt = 0; nt < 4; ++nt) oacc[nt][r] *= corr;
        }

        // write P strip to LDS (row-swizzled octets)
        #pragma unroll
        for (int r = 0; r < 4; ++r) {
            const int prow = g * 4 + r;
            const int swzr = (prow ^ (prow >> 3)) & 7;
            #pragma unroll
            for (int nt = 0; nt < 4; ++nt)
                Pw[prow * 64 + (((nt * 2 + (lc >> 3)) ^ swzr) * 8) + (lc & 7)]
                    = f2bf(p[nt][r]);
        }

        // O += P @ V   (P: swizzled b128 reads; V^T: swizzled b128 reads)
        #pragma unroll
        for (int kk = 0; kk < 2; ++kk) {
            const bf16x8 pa = *(const bf16x8*)
                &Pw[lc * 64 + (((kk * 4 + g) ^ swzl) * 8)];
            #pragma unroll
            for (int nt = 0; nt < 4; ++nt) {
                const int vrow = nt * 16 + lc;          // = d
                const bf16x8 vb = *(const bf16x8*)
                    &Vts[vrow * 64 + (((kk * 4 + g) ^ (lc & 7)) * 8)];
                oacc[nt] = MFMA_BF16(pa, vb, oacc[nt]);
            }
        }
    }

    // epilogue: normalize, store
    #pragma unroll
    for (int nt = 0; nt < 4; ++nt)
        #pragma unroll
        for (int r = 0; r < 4; ++r) {
            const float o = oacc[nt][r] / lrow[r];
            const size_t token = tok0 + qt * 64 + w * 16 + g * 4 + r;
            ctx[token * 1024 + h * 64 + nt * 16 + lc] = f2bf(o);
        }
}

// -----------------------------------------------------------------------------
extern "C" void kernel_launch(void* const* d_in, const int* in_sizes, int n_in,
                              void* d_out, int out_size, void* d_ws, size_t ws_size,
                              hipStream_t stream) {
    const float* x      = (const float*)d_in[0];
    const float* qkv_w  = (const float*)d_in[1];
    const float* out_w  = (const float*)d_in[2];
    const float* up_w   = (const float*)d_in[3];
    const float* down_w = (const float*)d_in[4];
    const float* n1s    = (const float*)d_in[5];
    const float* n1b    = (const float*)d_in[6];
    const float* n2s    = (const float*)d_in[7];
    const float* n2b    = (const float*)d_in[8];
    float* out = (float*)d_out;

    char* ws = (char*)d_ws;
    size_t off = 0;
    auto alloc = [&](size_t bytes) -> void* {
        void* p = ws + off;
        off += (bytes + 255) & ~(size_t)255;
        return p;
    };
    u16*   qkvw_b = (u16*)alloc(3072ull * 1024 * 2);
    u16*   outw_b = (u16*)alloc(1024ull * 1024 * 2);
    u16*   upw_b  = (u16*)alloc(4096ull * 1024 * 2);
    u16*   dnw_b  = (u16*)alloc(1024ull * 4096 * 2);
    u16*   h_b    = (u16*)alloc(4096ull * 1024 * 2);
    u16*   qkv_o  = (u16*)alloc(4096ull * 3072 * 2);
    u16*   ctx    = (u16*)alloc(4096ull * 1024 * 2);
    float* x2     = (float*)alloc(4096ull * 1024 * 4);
    u16*   u      = (u16*)alloc(4096ull * 4096 * 2);
    // vt aliases u: vt is live [tr_v_k .. attn_k], u is live [ffn-up .. ffn-down],
    // strictly stream-ordered after attn. 8 MB <= 32 MB.
    u16*   vt     = u;

    // weight conversions
    cvt_k<<<(3072 * 1024 / 4 + 255) / 256, 256, 0, stream>>>(qkv_w,  qkvw_b, 3072 * 1024 / 4);
    cvt_k<<<(1024 * 1024 / 4 + 255) / 256, 256, 0, stream>>>(out_w,  outw_b, 1024 * 1024 / 4);
    cvt_k<<<(4096 * 1024 / 4 + 255) / 256, 256, 0, stream>>>(up_w,   upw_b,  4096 * 1024 / 4);
    cvt_k<<<(1024 * 4096 / 4 + 255) / 256, 256, 0, stream>>>(down_w, dnw_b,  1024 * 4096 / 4);

    // --- attention sublayer ---
    ln_k<<<4096, 256, 0, stream>>>(x, h_b, n1s, n1b);
    gemm_bt_k<<<dim3(24, 32), 256, 0, stream>>>(h_b, qkvw_b, qkv_o, nullptr, nullptr,
                                                4096, 3072, 1024, 0);
    tr_v_k<<<dim3(32, 32), 256, 0, stream>>>(qkv_o, vt);
    attn_k<<<dim3(32, 32), 256, 0, stream>>>(qkv_o, vt, ctx);
    gemm_bt_k<<<dim3(8, 32), 256, 0, stream>>>(ctx, outw_b, nullptr, x2, x,
                                               4096, 1024, 1024, 1);

    // --- FFN sublayer ---
    ln_k<<<4096, 256, 0, stream>>>(x2, h_b, n2s, n2b);
    gemm_bt_k<<<dim3(32, 32), 256, 0, stream>>>(h_b, upw_b, u, nullptr, nullptr,
                                                4096, 4096, 1024, 2);
    gemm_bt_k<<<dim3(8, 32), 256, 0, stream>>>(u, dnw_b, nullptr, out, x2,
                                               4096, 1024, 4096, 1);
}

// Round 4
// 380.213 us; speedup vs baseline: 1.2665x; 1.0871x over previous
//
#include <hip/hip_runtime.h>

typedef unsigned short u16;
typedef unsigned int u32;
typedef __attribute__((ext_vector_type(8))) short bf16x8;
typedef __attribute__((ext_vector_type(4))) float f32x4;

#define MFMA_BF16(a, b, c) __builtin_amdgcn_mfma_f32_16x16x32_bf16((a), (b), (c), 0, 0, 0)
#define BAR() __builtin_amdgcn_s_barrier()
#define WAITV(n) asm volatile("s_waitcnt vmcnt(" #n ")" ::: "memory")

__device__ __forceinline__ u16 f2bf(float f) {
    u32 u = __builtin_bit_cast(u32, f);
    u32 r = u + 0x7FFFu + ((u >> 16) & 1u);   // round-to-nearest-even
    return (u16)(r >> 16);
}

__device__ __forceinline__ void gld16(const void* g, void* s) {
    __builtin_amdgcn_global_load_lds(
        (const __attribute__((address_space(1))) unsigned int*)g,
        (__attribute__((address_space(3))) unsigned int*)s, 16, 0, 0);
}

// ---------------- f32 -> bf16 convert (weights) ----------------
__global__ void cvt_k(const float* __restrict__ in, u16* __restrict__ out, int n4) {
    int i = blockIdx.x * blockDim.x + threadIdx.x;
    if (i >= n4) return;
    float4 v = ((const float4*)in)[i];
    ushort4 o;
    o.x = f2bf(v.x); o.y = f2bf(v.y); o.z = f2bf(v.z); o.w = f2bf(v.w);
    ((ushort4*)out)[i] = o;
}

// ---------------- LayerNorm (1024 cols) -> bf16 ----------------
__global__ __launch_bounds__(256) void ln_k(const float* __restrict__ x,
                                            u16* __restrict__ out,
                                            const float* __restrict__ sc,
                                            const float* __restrict__ bi) {
    const int row = blockIdx.x;
    const int tid = threadIdx.x;
    const float4 v = ((const float4*)(x + (size_t)row * 1024))[tid];
    float s  = v.x + v.y + v.z + v.w;
    float s2 = v.x*v.x + v.y*v.y + v.z*v.z + v.w*v.w;
    #pragma unroll
    for (int m = 32; m; m >>= 1) { s += __shfl_xor(s, m); s2 += __shfl_xor(s2, m); }
    __shared__ float red[8];
    const int w = tid >> 6, l = tid & 63;
    if (l == 0) { red[w] = s; red[4 + w] = s2; }
    __syncthreads();
    s  = red[0] + red[1] + red[2] + red[3];
    s2 = red[4] + red[5] + red[6] + red[7];
    const float mu  = s * (1.0f / 1024.0f);
    const float var = s2 * (1.0f / 1024.0f) - mu * mu;
    const float rs  = rsqrtf(var + 1e-5f);
    const float4 sv = ((const float4*)sc)[tid];
    const float4 bv = ((const float4*)bi)[tid];
    ushort4 o;
    o.x = f2bf((v.x - mu) * rs * sv.x + bv.x);
    o.y = f2bf((v.y - mu) * rs * sv.y + bv.y);
    o.z = f2bf((v.z - mu) * rs * sv.z + bv.z);
    o.w = f2bf((v.w - mu) * rs * sv.w + bv.w);
    ((ushort4*)(out + (size_t)row * 1024))[tid] = o;
}

// ---------------- 128^2-tile GEMM (2-phase, for small-N GEMMs) ---------------
__global__ __launch_bounds__(256) void gemm_bt_k(const u16* __restrict__ A,
                                                 const u16* __restrict__ B,
                                                 u16* __restrict__ Cb,
                                                 float* __restrict__ Cf,
                                                 const float* __restrict__ resid,
                                                 int M, int N, int K, int epi) {
    const int tid = threadIdx.x;
    const int w = tid >> 6, l = tid & 63, g = l >> 4, lc = l & 15;
    const int wr = w >> 1, wc = w & 1;
    const int row0 = blockIdx.y * 128, col0 = blockIdx.x * 128;

    __shared__ u16 As[128 * 32];
    __shared__ u16 Bs[128 * 32];

    f32x4 acc[4][4] = {};

    const int sr = tid >> 2, sq = tid & 3;
    const u16* ga = A + (size_t)(row0 + sr) * K + sq * 8;
    const u16* gb = B + (size_t)(col0 + sr) * K + sq * 8;
    const int nk = K >> 5;

    for (int kt = 0; kt < nk; ++kt) {
        __syncthreads();
        gld16(ga,                 (char*)As + tid * 16);
        gld16(ga + (size_t)64 * K, (char*)As + tid * 16 + 4096);
        gld16(gb,                 (char*)Bs + tid * 16);
        gld16(gb + (size_t)64 * K, (char*)Bs + tid * 16 + 4096);
        ga += 32; gb += 32;
        __syncthreads();

        bf16x8 af[4], bfr[4];
        #pragma unroll
        for (int i = 0; i < 4; ++i)
            af[i] = *(const bf16x8*)&As[(wr * 64 + i * 16 + lc) * 32 + g * 8];
        #pragma unroll
        for (int j = 0; j < 4; ++j)
            bfr[j] = *(const bf16x8*)&Bs[(wc * 64 + j * 16 + lc) * 32 + g * 8];
        #pragma unroll
        for (int i = 0; i < 4; ++i)
            #pragma unroll
            for (int j = 0; j < 4; ++j)
                acc[i][j] = MFMA_BF16(af[i], bfr[j], acc[i][j]);
    }

    #pragma unroll
    for (int i = 0; i < 4; ++i)
        #pragma unroll
        for (int j = 0; j < 4; ++j)
            #pragma unroll
            for (int r = 0; r < 4; ++r) {
                const int row = row0 + wr * 64 + i * 16 + g * 4 + r;
                const int col = col0 + wc * 64 + j * 16 + lc;
                const size_t off = (size_t)row * N + col;
                const float v = acc[i][j][r];
                if (epi == 0) {
                    Cb[off] = f2bf(v);
                } else if (epi == 1) {
                    Cf[off] = v + resid[off];
                } else {
                    const float gv = 0.5f * v * (1.0f + erff(v * 0.70710678118f));
                    Cb[off] = f2bf(gv);
                }
            }
}

// ---------------- 256^2-tile deep-pipelined GEMM (counted vmcnt) -------------
// 8 waves (2Mx4N), per-wave 128x64 out. BK=32. 4-slot LDS ring (128 KiB),
// prefetch distance 3; steady-state s_waitcnt vmcnt(10), never 0 in loop.
// Slot for tile t+3 == slot of tile t-1; every wave is past tile t-1's closing
// barrier before any wave can issue that stage (barriers totally ordered).
template<int NT, int EPI>
__global__ __launch_bounds__(512, 1) void gemm256_k(const u16* __restrict__ A,
                                                    const u16* __restrict__ B,
                                                    u16* __restrict__ Cb,
                                                    float* __restrict__ Cf,
                                                    const float* __restrict__ resid,
                                                    int M, int N, int K) {
    extern __shared__ u16 L[];          // 4 slots x (A 16384B + B 16384B)
    const int tid = threadIdx.x;
    const int w = tid >> 6, l = tid & 63, g = l >> 4, lc = l & 15;
    const int wr = w >> 2, wc = w & 3;
    const int row0 = blockIdx.y * 256, col0 = blockIdx.x * 256;

    const int c0 = tid, r0s = c0 >> 2, q0 = c0 & 3;
    const int c1 = tid + 512, r1s = c1 >> 2, q1 = c1 & 3;
    const u16* gA = A + (size_t)row0 * K;
    const u16* gB = B + (size_t)col0 * K;

#define STAGE_A(t) do { \
        char* dA_ = (char*)&L[((t) & 3) * 16384]; \
        gld16(gA + (size_t)r0s * K + (t) * 32 + q0 * 8, dA_ + c0 * 16); \
        gld16(gA + (size_t)r1s * K + (t) * 32 + q1 * 8, dA_ + c1 * 16); \
    } while (0)
#define STAGE_B(t) do { \
        char* dB_ = (char*)&L[((t) & 3) * 16384] + 16384; \
        gld16(gB + (size_t)r0s * K + (t) * 32 + q0 * 8, dB_ + c0 * 16); \
        gld16(gB + (size_t)r1s * K + (t) * 32 + q1 * 8, dB_ + c1 * 16); \
    } while (0)

    f32x4 acc[8][4] = {};

    STAGE_A(0); STAGE_B(0);
    STAGE_A(1); STAGE_B(1);
    STAGE_A(2); STAGE_B(2);

    for (int t = 0; t < NT; ++t) {
        if (t + 3 < NT) STAGE_A(t + 3);
        if      (t < NT - 3) WAITV(10);
        else if (t == NT - 3) WAITV(8);
        else if (t == NT - 2) WAITV(4);
        else                  WAITV(0);
        BAR();

        const u16* Lb = &L[(t & 3) * 16384];
        bf16x8 af[4], bfr[4];
        #pragma unroll
        for (int i = 0; i < 4; ++i)
            af[i] = *(const bf16x8*)&Lb[(wr * 128 + i * 16 + lc) * 32 + g * 8];
        #pragma unroll
        for (int j = 0; j < 4; ++j)
            bfr[j] = *(const bf16x8*)&Lb[8192 + (wc * 64 + j * 16 + lc) * 32 + g * 8];

        __builtin_amdgcn_s_setprio(1);
        #pragma unroll
        for (int i = 0; i < 4; ++i)
            #pragma unroll
            for (int j = 0; j < 4; ++j)
                acc[i][j] = MFMA_BF16(af[i], bfr[j], acc[i][j]);
        __builtin_amdgcn_s_setprio(0);

        if (t + 3 < NT) STAGE_B(t + 3);

        bf16x8 af2[4];
        #pragma unroll
        for (int i = 0; i < 4; ++i)
            af2[i] = *(const bf16x8*)&Lb[(wr * 128 + 64 + i * 16 + lc) * 32 + g * 8];

        __builtin_amdgcn_s_setprio(1);
        #pragma unroll
        for (int i = 0; i < 4; ++i)
            #pragma unroll
            for (int j = 0; j < 4; ++j)
                acc[4 + i][j] = MFMA_BF16(af2[i], bfr[j], acc[4 + i][j]);
        __builtin_amdgcn_s_setprio(0);
        BAR();
    }
#undef STAGE_A
#undef STAGE_B

    #pragma unroll
    for (int i = 0; i < 8; ++i)
        #pragma unroll
        for (int j = 0; j < 4; ++j)
            #pragma unroll
            for (int r = 0; r < 4; ++r) {
                const int row = row0 + wr * 128 + i * 16 + g * 4 + r;
                const int col = col0 + wc * 64 + j * 16 + lc;
                const size_t off = (size_t)row * N + col;
                const float v = acc[i][j][r];
                if (EPI == 0) {
                    Cb[off] = f2bf(v);
                } else if (EPI == 1) {
                    Cf[off] = v + resid[off];
                } else {
                    const float gv = 0.5f * v * (1.0f + erff(v * 0.70710678118f));
                    Cb[off] = f2bf(gv);
                }
            }
}

// ---------------- V transpose: qkv V-part [token][h*64+d] -> vt[bh][d][token] --
__global__ __launch_bounds__(256) void tr_v_k(const u16* __restrict__ qkv,
                                              u16* __restrict__ vt) {
    const int tt = blockIdx.x;          // token tile 0..31
    const int bh = blockIdx.y;          // 0..31
    const int b = bh >> 4, h = bh & 15;
    const u16* src = qkv + (size_t)(b * 2048 + tt * 64) * 3072 + 2048 + h * 64;
    u16* dst = vt + (size_t)bh * 64 * 2048 + tt * 64;

    __shared__ u16 T[64 * 64];          // swizzled: V[row][d] at row*64 + ((d>>3)^(row&7))*8 + (d&7)

    #pragma unroll
    for (int it = 0; it < 2; ++it) {
        const int idx = it * 256 + threadIdx.x;
        const int trow = idx >> 3, oct = idx & 7;
        const uint4 v = *(const uint4*)(src + (size_t)trow * 3072 + oct * 8);
        *(uint4*)&T[trow * 64 + ((oct ^ (trow & 7)) * 8)] = v;
    }
    __syncthreads();
    #pragma unroll
    for (int it = 0; it < 2; ++it) {
        const int idx = it * 256 + threadIdx.x;
        const int d = idx >> 3, t8 = idx & 7;
        ushort vals[8];
        #pragma unroll
        for (int j = 0; j < 8; ++j) {
            const int row = t8 * 8 + j;
            vals[j] = T[row * 64 + (((d >> 3) ^ (row & 7)) * 8) + (d & 7)];
        }
        *(uint4*)(dst + (size_t)d * 2048 + t8 * 8) = *(const uint4*)vals;
    }
}

// ---------------- Flash attention: B=2, H=16, S=2048, D=64 -------------------
__global__ __launch_bounds__(256) void attn_k(const u16* __restrict__ qkv,
                                              const u16* __restrict__ vt,
                                              u16* __restrict__ ctx) {
    const int qt = blockIdx.x;          // 0..31  (q tile of 64 rows)
    const int bh = blockIdx.y;          // 0..31
    const int b = bh >> 4, h = bh & 15;
    const int tid = threadIdx.x, w = tid >> 6, l = tid & 63, g = l >> 4, lc = l & 15;
    const size_t tok0 = (size_t)b * 2048;

    const u16* Qg  = qkv + (tok0 + qt * 64) * 3072 + h * 64;
    const u16* Kg  = qkv + tok0 * 3072 + 1024 + h * 64;
    const u16* Vtg = vt + (size_t)bh * 64 * 2048;      // [d][token-in-batch]

    __shared__ u16 Ks[64 * 64];
    __shared__ u16 Vts[64 * 64];        // [d][key] swizzled like Ks
    __shared__ u16 QPs[64 * 64];        // Q tile in prologue, then P strips (1024 u16/wave)
    u16* Pw = QPs + w * 1024;

    // stage Q tile (swizzled source, linear dest)
    {
        int s = tid;
        int row = s >> 3, c = (s & 7) ^ (row & 7);
        gld16(Qg + (size_t)row * 3072 + c * 8, (char*)QPs + s * 16);
        s = tid + 256;
        row = s >> 3; c = (s & 7) ^ (row & 7);
        gld16(Qg + (size_t)row * 3072 + c * 8, (char*)QPs + s * 16);
    }
    __syncthreads();
    bf16x8 qf[2];
    {
        const int qrow = w * 16 + lc;
        qf[0] = *(const bf16x8*)&QPs[qrow * 64 + ((g       ^ (lc & 7)) * 8)];
        qf[1] = *(const bf16x8*)&QPs[qrow * 64 + (((4 + g) ^ (lc & 7)) * 8)];
    }

    f32x4 oacc[4] = {};
    float mrow[4], lrow[4];
    #pragma unroll
    for (int r = 0; r < 4; ++r) { mrow[r] = -1e30f; lrow[r] = 0.0f; }

    const float scl = 0.125f * 1.44269504f;   // /sqrt(64) * log2(e): softmax in 2^x domain
    const int swzl = (lc ^ (lc >> 3)) & 7;    // P-read row swizzle for this lane

    for (int kt = 0; kt < 32; ++kt) {
        __syncthreads();
        // stage K + V^T tiles (swizzled source, linear dest)
        {
            int s = tid;
            int row = s >> 3;
            int c = (s & 7) ^ (row & 7);
            gld16(Kg  + (size_t)(kt * 64 + row) * 3072 + c * 8, (char*)Ks + s * 16);
            gld16(Vtg + (size_t)row * 2048 + kt * 64 + c * 8,   (char*)Vts + s * 16);
            s = tid + 256;
            row = s >> 3;
            c = (s & 7) ^ (row & 7);
            gld16(Kg  + (size_t)(kt * 64 + row) * 3072 + c * 8, (char*)Ks + s * 16);
            gld16(Vtg + (size_t)row * 2048 + kt * 64 + c * 8,   (char*)Vts + s * 16);
        }
        __syncthreads();

        // S strip (16 x 64) = Q_strip @ K^T  (swizzled K reads: conflict-free)
        f32x4 sacc[4] = {};
        #pragma unroll
        for (int kk = 0; kk < 2; ++kk)
            #pragma unroll
            for (int nt = 0; nt < 4; ++nt) {
                const int krow = nt * 16 + lc;
                const bf16x8 kb = *(const bf16x8*)
                    &Ks[krow * 64 + (((kk * 4 + g) ^ (lc & 7)) * 8)];
                sacc[nt] = MFMA_BF16(qf[kk], kb, sacc[nt]);
            }

        // online softmax on the strip (log2 domain)
        float p[4][4];
        #pragma unroll
        for (int r = 0; r < 4; ++r) {
            float mx = -1e30f;
            #pragma unroll
            for (int nt = 0; nt < 4; ++nt) {
                sacc[nt][r] *= scl;
                mx = fmaxf(mx, sacc[nt][r]);
            }
            #pragma unroll
            for (int mm = 1; mm < 16; mm <<= 1) mx = fmaxf(mx, __shfl_xor(mx, mm));
            const float mnew = fmaxf(mrow[r], mx);
            const float corr = exp2f(mrow[r] - mnew);
            float ps = 0.0f;
            #pragma unroll
            for (int nt = 0; nt < 4; ++nt) {
                const float pv = exp2f(sacc[nt][r] - mnew);
                p[nt][r] = pv;
                ps += pv;
            }
            #pragma unroll
            for (int mm = 1; mm < 16; mm <<= 1) ps += __shfl_xor(ps, mm);
            lrow[r] = lrow[r] * corr + ps;
            mrow[r] = mnew;
            #pragma unroll
            for (int nt = 0; nt < 4; ++nt) oacc[nt][r] *= corr;
        }

        // write P strip to LDS (row-swizzled octets)
        #pragma unroll
        for (int r = 0; r < 4; ++r) {
            const int prow = g * 4 + r;
            const int swzr = (prow ^ (prow >> 3)) & 7;
            #pragma unroll
            for (int nt = 0; nt < 4; ++nt)
                Pw[prow * 64 + (((nt * 2 + (lc >> 3)) ^ swzr) * 8) + (lc & 7)]
                    = f2bf(p[nt][r]);
        }

        // O += P @ V   (P: swizzled b128 reads; V^T: swizzled b128 reads)
        #pragma unroll
        for (int kk = 0; kk < 2; ++kk) {
            const bf16x8 pa = *(const bf16x8*)
                &Pw[lc * 64 + (((kk * 4 + g) ^ swzl) * 8)];
            #pragma unroll
            for (int nt = 0; nt < 4; ++nt) {
                const int vrow = nt * 16 + lc;          // = d
                const bf16x8 vb = *(const bf16x8*)
                    &Vts[vrow * 64 + (((kk * 4 + g) ^ (lc & 7)) * 8)];
                oacc[nt] = MFMA_BF16(pa, vb, oacc[nt]);
            }
        }
    }

    // epilogue: normalize, store
    #pragma unroll
    for (int nt = 0; nt < 4; ++nt)
        #pragma unroll
        for (int r = 0; r < 4; ++r) {
            const float o = oacc[nt][r] / lrow[r];
            const size_t token = tok0 + qt * 64 + w * 16 + g * 4 + r;
            ctx[token * 1024 + h * 64 + nt * 16 + lc] = f2bf(o);
        }
}

// -----------------------------------------------------------------------------
extern "C" void kernel_launch(void* const* d_in, const int* in_sizes, int n_in,
                              void* d_out, int out_size, void* d_ws, size_t ws_size,
                              hipStream_t stream) {
    const float* x      = (const float*)d_in[0];
    const float* qkv_w  = (const float*)d_in[1];
    const float* out_w  = (const float*)d_in[2];
    const float* up_w   = (const float*)d_in[3];
    const float* down_w = (const float*)d_in[4];
    const float* n1s    = (const float*)d_in[5];
    const float* n1b    = (const float*)d_in[6];
    const float* n2s    = (const float*)d_in[7];
    const float* n2b    = (const float*)d_in[8];
    float* out = (float*)d_out;

    char* ws = (char*)d_ws;
    size_t off = 0;
    auto alloc = [&](size_t bytes) -> void* {
        void* p = ws + off;
        off += (bytes + 255) & ~(size_t)255;
        return p;
    };
    u16*   qkvw_b = (u16*)alloc(3072ull * 1024 * 2);
    u16*   outw_b = (u16*)alloc(1024ull * 1024 * 2);
    u16*   upw_b  = (u16*)alloc(4096ull * 1024 * 2);
    u16*   dnw_b  = (u16*)alloc(1024ull * 4096 * 2);
    u16*   h_b    = (u16*)alloc(4096ull * 1024 * 2);
    u16*   qkv_o  = (u16*)alloc(4096ull * 3072 * 2);
    u16*   ctx    = (u16*)alloc(4096ull * 1024 * 2);
    float* x2     = (float*)alloc(4096ull * 1024 * 4);
    u16*   u      = (u16*)alloc(4096ull * 4096 * 2);
    // vt aliases u: vt live [tr_v_k .. attn_k]; u live [ffn-up .. ffn-down].
    u16*   vt     = u;

    // allow 128 KiB dynamic LDS for the 256^2 template
    hipFuncSetAttribute((const void*)&gemm256_k<32, 0>,
                        hipFuncAttributeMaxDynamicSharedMemorySize, 131072);
    hipFuncSetAttribute((const void*)&gemm256_k<32, 2>,
                        hipFuncAttributeMaxDynamicSharedMemorySize, 131072);

    // weight conversions
    cvt_k<<<(3072 * 1024 / 4 + 255) / 256, 256, 0, stream>>>(qkv_w,  qkvw_b, 3072 * 1024 / 4);
    cvt_k<<<(1024 * 1024 / 4 + 255) / 256, 256, 0, stream>>>(out_w,  outw_b, 1024 * 1024 / 4);
    cvt_k<<<(4096 * 1024 / 4 + 255) / 256, 256, 0, stream>>>(up_w,   upw_b,  4096 * 1024 / 4);
    cvt_k<<<(1024 * 4096 / 4 + 255) / 256, 256, 0, stream>>>(down_w, dnw_b,  1024 * 4096 / 4);

    // --- attention sublayer ---
    ln_k<<<4096, 256, 0, stream>>>(x, h_b, n1s, n1b);
    gemm256_k<32, 0><<<dim3(12, 16), 512, 131072, stream>>>(h_b, qkvw_b, qkv_o,
                                                            nullptr, nullptr,
                                                            4096, 3072, 1024);
    tr_v_k<<<dim3(32, 32), 256, 0, stream>>>(qkv_o, vt);
    attn_k<<<dim3(32, 32), 256, 0, stream>>>(qkv_o, vt, ctx);
    gemm_bt_k<<<dim3(8, 32), 256, 0, stream>>>(ctx, outw_b, nullptr, x2, x,
                                               4096, 1024, 1024, 1);

    // --- FFN sublayer ---
    ln_k<<<4096, 256, 0, stream>>>(x2, h_b, n2s, n2b);
    gemm256_k<32, 2><<<dim3(16, 16), 512, 131072, stream>>>(h_b, upw_b, u,
                                                            nullptr, nullptr,
                                                            4096, 4096, 1024);
    gemm_bt_k<<<dim3(8, 32), 256, 0, stream>>>(u, dnw_b, nullptr, out, x2,
                                               4096, 1024, 4096, 1);
}

// Round 5
// 272.675 us; speedup vs baseline: 1.7659x; 1.3944x over previous
//
#include <hip/hip_runtime.h>

typedef unsigned short u16;
typedef unsigned int u32;
typedef __attribute__((ext_vector_type(8))) short bf16x8;
typedef __attribute__((ext_vector_type(4))) float f32x4;

#define MFMA_BF16(a, b, c) __builtin_amdgcn_mfma_f32_16x16x32_bf16((a), (b), (c), 0, 0, 0)
#define BAR() __builtin_amdgcn_s_barrier()
#define WAITV(n) asm volatile("s_waitcnt vmcnt(" #n ")" ::: "memory")

__device__ __forceinline__ u16 f2bf(float f) {
    u32 u = __builtin_bit_cast(u32, f);
    u32 r = u + 0x7FFFu + ((u >> 16) & 1u);   // round-to-nearest-even
    return (u16)(r >> 16);
}

__device__ __forceinline__ void gld16(const void* g, void* s) {
    __builtin_amdgcn_global_load_lds(
        (const __attribute__((address_space(1))) unsigned int*)g,
        (__attribute__((address_space(3))) unsigned int*)s, 16, 0, 0);
}

// ---------------- f32 -> bf16 convert (weights) ----------------
__global__ void cvt_k(const float* __restrict__ in, u16* __restrict__ out, int n4) {
    int i = blockIdx.x * blockDim.x + threadIdx.x;
    if (i >= n4) return;
    float4 v = ((const float4*)in)[i];
    ushort4 o;
    o.x = f2bf(v.x); o.y = f2bf(v.y); o.z = f2bf(v.z); o.w = f2bf(v.w);
    ((ushort4*)out)[i] = o;
}

// ---------------- LayerNorm (1024 cols) -> bf16 ----------------
__global__ __launch_bounds__(256) void ln_k(const float* __restrict__ x,
                                            u16* __restrict__ out,
                                            const float* __restrict__ sc,
                                            const float* __restrict__ bi) {
    const int row = blockIdx.x;
    const int tid = threadIdx.x;
    const float4 v = ((const float4*)(x + (size_t)row * 1024))[tid];
    float s  = v.x + v.y + v.z + v.w;
    float s2 = v.x*v.x + v.y*v.y + v.z*v.z + v.w*v.w;
    #pragma unroll
    for (int m = 32; m; m >>= 1) { s += __shfl_xor(s, m); s2 += __shfl_xor(s2, m); }
    __shared__ float red[8];
    const int w = tid >> 6, l = tid & 63;
    if (l == 0) { red[w] = s; red[4 + w] = s2; }
    __syncthreads();
    s  = red[0] + red[1] + red[2] + red[3];
    s2 = red[4] + red[5] + red[6] + red[7];
    const float mu  = s * (1.0f / 1024.0f);
    const float var = s2 * (1.0f / 1024.0f) - mu * mu;
    const float rs  = rsqrtf(var + 1e-5f);
    const float4 sv = ((const float4*)sc)[tid];
    const float4 bv = ((const float4*)bi)[tid];
    ushort4 o;
    o.x = f2bf((v.x - mu) * rs * sv.x + bv.x);
    o.y = f2bf((v.y - mu) * rs * sv.y + bv.y);
    o.z = f2bf((v.z - mu) * rs * sv.z + bv.z);
    o.w = f2bf((v.w - mu) * rs * sv.w + bv.w);
    ((ushort4*)(out + (size_t)row * 1024))[tid] = o;
}

// ---------------- 256^2-tile deep-pipelined GEMM (counted vmcnt) -------------
// 8 waves (2Mx4N). BK=32. 4-slot LDS ring (128 KiB), prefetch distance 3;
// steady-state vmcnt(10), never 0 in loop. LDS octet swizzle: stored octet =
// orig ^ (row&3) via pre-swizzled global source; reads XOR g^(lc&3).
// EPI 0: store bf16, scaling cols<1024 by 0.125*log2e (qkv: pre-scales Q).
// EPI 2: exact gelu -> bf16.
template<int NT, int EPI>
__global__ __launch_bounds__(512, 1) void gemm256_k(const u16* __restrict__ A,
                                                    const u16* __restrict__ B,
                                                    u16* __restrict__ Cb,
                                                    float* __restrict__ Cf,
                                                    const float* __restrict__ resid,
                                                    int M, int N, int K) {
    extern __shared__ u16 L[];          // 4 slots x (A 16384B + B 16384B)
    const int tid = threadIdx.x;
    const int w = tid >> 6, l = tid & 63, g = l >> 4, lc = l & 15;
    const int wr = w >> 2, wc = w & 3;
    const int row0 = blockIdx.y * 256, col0 = blockIdx.x * 256;

    const int c0 = tid, r0s = c0 >> 2;
    const int c1 = tid + 512, r1s = c1 >> 2;
    const int qs = (tid & 3) ^ ((tid >> 2) & 3);
    const u16* gA = A + (size_t)row0 * K;
    const u16* gB = B + (size_t)col0 * K;

#define STAGE_A(t) do { \
        char* dA_ = (char*)&L[((t) & 3) * 16384]; \
        gld16(gA + (size_t)r0s * K + (t) * 32 + qs * 8, dA_ + c0 * 16); \
        gld16(gA + (size_t)r1s * K + (t) * 32 + qs * 8, dA_ + c1 * 16); \
    } while (0)
#define STAGE_B(t) do { \
        char* dB_ = (char*)&L[((t) & 3) * 16384] + 16384; \
        gld16(gB + (size_t)r0s * K + (t) * 32 + qs * 8, dB_ + c0 * 16); \
        gld16(gB + (size_t)r1s * K + (t) * 32 + qs * 8, dB_ + c1 * 16); \
    } while (0)

    f32x4 acc[8][4] = {};

    STAGE_A(0); STAGE_B(0);
    STAGE_A(1); STAGE_B(1);
    STAGE_A(2); STAGE_B(2);

    const int oc = (g ^ (lc & 3)) * 8;

    for (int t = 0; t < NT; ++t) {
        if (t + 3 < NT) STAGE_A(t + 3);
        if      (t < NT - 3) WAITV(10);
        else if (t == NT - 3) WAITV(8);
        else if (t == NT - 2) WAITV(4);
        else                  WAITV(0);
        BAR();

        const u16* Lb = &L[(t & 3) * 16384];
        bf16x8 af[4], bfr[4];
        #pragma unroll
        for (int i = 0; i < 4; ++i)
            af[i] = *(const bf16x8*)&Lb[(wr * 128 + i * 16 + lc) * 32 + oc];
        #pragma unroll
        for (int j = 0; j < 4; ++j)
            bfr[j] = *(const bf16x8*)&Lb[8192 + (wc * 64 + j * 16 + lc) * 32 + oc];

        __builtin_amdgcn_s_setprio(1);
        #pragma unroll
        for (int i = 0; i < 4; ++i)
            #pragma unroll
            for (int j = 0; j < 4; ++j)
                acc[i][j] = MFMA_BF16(af[i], bfr[j], acc[i][j]);
        __builtin_amdgcn_s_setprio(0);

        if (t + 3 < NT) STAGE_B(t + 3);

        bf16x8 af2[4];
        #pragma unroll
        for (int i = 0; i < 4; ++i)
            af2[i] = *(const bf16x8*)&Lb[(wr * 128 + 64 + i * 16 + lc) * 32 + oc];

        __builtin_amdgcn_s_setprio(1);
        #pragma unroll
        for (int i = 0; i < 4; ++i)
            #pragma unroll
            for (int j = 0; j < 4; ++j)
                acc[4 + i][j] = MFMA_BF16(af2[i], bfr[j], acc[4 + i][j]);
        __builtin_amdgcn_s_setprio(0);
        BAR();
    }
#undef STAGE_A
#undef STAGE_B

    #pragma unroll
    for (int i = 0; i < 8; ++i)
        #pragma unroll
        for (int j = 0; j < 4; ++j)
            #pragma unroll
            for (int r = 0; r < 4; ++r) {
                const int row = row0 + wr * 128 + i * 16 + g * 4 + r;
                const int col = col0 + wc * 64 + j * 16 + lc;
                const size_t off = (size_t)row * N + col;
                const float v = acc[i][j][r];
                if (EPI == 0) {
                    const float vv = (col < 1024) ? v * 0.180336880f : v;
                    Cb[off] = f2bf(vv);
                } else if (EPI == 1) {
                    Cf[off] = v + resid[off];
                } else {
                    const float gv = 0.5f * v * (1.0f + erff(v * 0.70710678118f));
                    Cb[off] = f2bf(gv);
                }
            }
}

// ---------------- 128^2-tile deep-pipelined GEMM (counted vmcnt) -------------
// 4 waves (2x2), BK=32, 4-slot ring (64 KiB), prefetch distance 3, vmcnt(10).
template<int NT, int EPI>
__global__ __launch_bounds__(256) void gemm128p_k(const u16* __restrict__ A,
                                                  const u16* __restrict__ B,
                                                  u16* __restrict__ Cb,
                                                  float* __restrict__ Cf,
                                                  const float* __restrict__ resid,
                                                  int M, int N, int K) {
    extern __shared__ u16 L[];          // 4 slots x (A 8192B + B 8192B)
    const int tid = threadIdx.x;
    const int w = tid >> 6, l = tid & 63, g = l >> 4, lc = l & 15;
    const int wr = w >> 1, wc = w & 1;
    const int row0 = blockIdx.y * 128, col0 = blockIdx.x * 128;

    const int sr = tid >> 2;
    const int qs = (tid & 3) ^ (sr & 3);
    const u16* ga = A + (size_t)(row0 + sr) * K + qs * 8;
    const u16* gb = B + (size_t)(col0 + sr) * K + qs * 8;

#define PSTAGE_A(t) do { \
        char* d_ = (char*)&L[((t) & 3) * 8192]; \
        gld16(ga + (size_t)(t) * 32,                d_ + tid * 16); \
        gld16(ga + (size_t)64 * K + (size_t)(t) * 32, d_ + tid * 16 + 4096); \
    } while (0)
#define PSTAGE_B(t) do { \
        char* d_ = (char*)&L[((t) & 3) * 8192] + 8192; \
        gld16(gb + (size_t)(t) * 32,                d_ + tid * 16); \
        gld16(gb + (size_t)64 * K + (size_t)(t) * 32, d_ + tid * 16 + 4096); \
    } while (0)

    f32x4 acc[4][4] = {};

    PSTAGE_A(0); PSTAGE_B(0);
    PSTAGE_A(1); PSTAGE_B(1);
    PSTAGE_A(2); PSTAGE_B(2);

    const int oc = (g ^ (lc & 3)) * 8;

    for (int t = 0; t < NT; ++t) {
        if (t + 3 < NT) PSTAGE_A(t + 3);
        if      (t < NT - 3) WAITV(10);
        else if (t == NT - 3) WAITV(8);
        else if (t == NT - 2) WAITV(4);
        else                  WAITV(0);
        BAR();

        const u16* Ls = &L[(t & 3) * 8192];
        bf16x8 af[4], bfr[4];
        #pragma unroll
        for (int i = 0; i < 4; ++i)
            af[i] = *(const bf16x8*)&Ls[(wr * 64 + i * 16 + lc) * 32 + oc];
        #pragma unroll
        for (int j = 0; j < 4; ++j)
            bfr[j] = *(const bf16x8*)&Ls[4096 + (wc * 64 + j * 16 + lc) * 32 + oc];

        if (t + 3 < NT) PSTAGE_B(t + 3);

        __builtin_amdgcn_s_setprio(1);
        #pragma unroll
        for (int i = 0; i < 4; ++i)
            #pragma unroll
            for (int j = 0; j < 4; ++j)
                acc[i][j] = MFMA_BF16(af[i], bfr[j], acc[i][j]);
        __builtin_amdgcn_s_setprio(0);
        BAR();
    }
#undef PSTAGE_A
#undef PSTAGE_B

    #pragma unroll
    for (int i = 0; i < 4; ++i)
        #pragma unroll
        for (int j = 0; j < 4; ++j)
            #pragma unroll
            for (int r = 0; r < 4; ++r) {
                const int row = row0 + wr * 64 + i * 16 + g * 4 + r;
                const int col = col0 + wc * 64 + j * 16 + lc;
                const size_t off = (size_t)row * N + col;
                const float v = acc[i][j][r];
                if (EPI == 0) {
                    Cb[off] = f2bf(v);
                } else if (EPI == 1) {
                    Cf[off] = v + resid[off];
                } else {
                    const float gv = 0.5f * v * (1.0f + erff(v * 0.70710678118f));
                    Cb[off] = f2bf(gv);
                }
            }
}

// ---------------- V transpose: qkv V-part [token][h*64+d] -> vt[bh][d][token] --
__global__ __launch_bounds__(256) void tr_v_k(const u16* __restrict__ qkv,
                                              u16* __restrict__ vt) {
    const int tt = blockIdx.x;          // token tile 0..31
    const int bh = blockIdx.y;          // 0..31
    const int b = bh >> 4, h = bh & 15;
    const u16* src = qkv + (size_t)(b * 2048 + tt * 64) * 3072 + 2048 + h * 64;
    u16* dst = vt + (size_t)bh * 64 * 2048 + tt * 64;

    __shared__ u16 T[64 * 64];          // swizzled: V[row][d] at row*64 + ((d>>3)^(row&7))*8 + (d&7)

    #pragma unroll
    for (int it = 0; it < 2; ++it) {
        const int idx = it * 256 + threadIdx.x;
        const int trow = idx >> 3, oct = idx & 7;
        const uint4 v = *(const uint4*)(src + (size_t)trow * 3072 + oct * 8);
        *(uint4*)&T[trow * 64 + ((oct ^ (trow & 7)) * 8)] = v;
    }
    __syncthreads();
    #pragma unroll
    for (int it = 0; it < 2; ++it) {
        const int idx = it * 256 + threadIdx.x;
        const int d = idx >> 3, t8 = idx & 7;
        ushort vals[8];
        #pragma unroll
        for (int j = 0; j < 8; ++j) {
            const int row = t8 * 8 + j;
            vals[j] = T[row * 64 + (((d >> 3) ^ (row & 7)) * 8) + (d & 7)];
        }
        *(uint4*)(dst + (size_t)d * 2048 + t8 * 8) = *(const uint4*)vals;
    }
}

// ---------------- Flash attention: B=2, H=16, S=2048, D=64 -------------------
// Swapped QK^T: sacc = mfma(K,Q) so each lane holds 16 P values for ONE q=lc.
// Softmax is in-lane + 2 shfl_xor; P packed to LDS as 4 ds_write_b64 (swizzled).
// Q pre-scaled by 0.125*log2e in the QKV GEMM epilogue.
__global__ __launch_bounds__(256) void attn_k(const u16* __restrict__ qkv,
                                              const u16* __restrict__ vt,
                                              u16* __restrict__ ctx) {
    const int qt = blockIdx.x;          // 0..31  (q tile of 64 rows)
    const int bh = blockIdx.y;          // 0..31
    const int b = bh >> 4, h = bh & 15;
    const int tid = threadIdx.x, w = tid >> 6, l = tid & 63, g = l >> 4, lc = l & 15;
    const size_t tok0 = (size_t)b * 2048;

    const u16* Qg  = qkv + (tok0 + qt * 64) * 3072 + h * 64;
    const u16* Kg  = qkv + tok0 * 3072 + 1024 + h * 64;
    const u16* Vtg = vt + (size_t)bh * 64 * 2048;      // [d][token-in-batch]

    __shared__ u16 Ks[64 * 64];
    __shared__ u16 Vts[64 * 64];        // [d][key] swizzled like Ks
    __shared__ u16 QPs[64 * 64];        // Q tile in prologue, then P strips (1024 u16/wave)
    u16* Pw = QPs + w * 1024;

    // stage Q tile (swizzled source, linear dest)
    {
        int s = tid;
        int row = s >> 3, c = (s & 7) ^ (row & 7);
        gld16(Qg + (size_t)row * 3072 + c * 8, (char*)QPs + s * 16);
        s = tid + 256;
        row = s >> 3; c = (s & 7) ^ (row & 7);
        gld16(Qg + (size_t)row * 3072 + c * 8, (char*)QPs + s * 16);
    }
    __syncthreads();
    bf16x8 qf[2];
    {
        const int qrow = w * 16 + lc;
        qf[0] = *(const bf16x8*)&QPs[qrow * 64 + ((g       ^ (lc & 7)) * 8)];
        qf[1] = *(const bf16x8*)&QPs[qrow * 64 + (((4 + g) ^ (lc & 7)) * 8)];
    }

    f32x4 oacc[4] = {};
    float mrow = -1e30f, lrow = 0.0f;   // per-lane: q = lc
    const int hsw = (lc & 7) << 3;      // P row swizzle (u16 units, 16B granules)

    for (int kt = 0; kt < 32; ++kt) {
        __syncthreads();
        // stage K + V^T tiles (swizzled source, linear dest)
        {
            int s = tid;
            int row = s >> 3;
            int c = (s & 7) ^ (row & 7);
            gld16(Kg  + (size_t)(kt * 64 + row) * 3072 + c * 8, (char*)Ks + s * 16);
            gld16(Vtg + (size_t)row * 2048 + kt * 64 + c * 8,   (char*)Vts + s * 16);
            s = tid + 256;
            row = s >> 3;
            c = (s & 7) ^ (row & 7);
            gld16(Kg  + (size_t)(kt * 64 + row) * 3072 + c * 8, (char*)Ks + s * 16);
            gld16(Vtg + (size_t)row * 2048 + kt * 64 + c * 8,   (char*)Vts + s * 16);
        }
        __syncthreads();

        // S^T strip: sacc[nt] holds S[key = nt*16+g*4+r][q = lc]
        f32x4 sacc[4] = {};
        __builtin_amdgcn_s_setprio(1);
        #pragma unroll
        for (int kk = 0; kk < 2; ++kk)
            #pragma unroll
            for (int nt = 0; nt < 4; ++nt) {
                const int krow = nt * 16 + lc;
                const bf16x8 kb = *(const bf16x8*)
                    &Ks[krow * 64 + (((kk * 4 + g) ^ (lc & 7)) * 8)];
                sacc[nt] = MFMA_BF16(kb, qf[kk], sacc[nt]);
            }
        __builtin_amdgcn_s_setprio(0);

        // online softmax: in-lane over 16 + cross-g reduce (2 shfls)
        float mx = sacc[0][0];
        #pragma unroll
        for (int nt = 0; nt < 4; ++nt)
            #pragma unroll
            for (int r = 0; r < 4; ++r)
                mx = fmaxf(mx, sacc[nt][r]);
        mx = fmaxf(mx, __shfl_xor(mx, 16));
        mx = fmaxf(mx, __shfl_xor(mx, 32));
        const float mnew = fmaxf(mrow, mx);
        const float corr = exp2f(mrow - mnew);
        mrow = mnew;

        float p[4][4];
        float ps = 0.0f;
        #pragma unroll
        for (int nt = 0; nt < 4; ++nt)
            #pragma unroll
            for (int r = 0; r < 4; ++r) {
                const float pv = exp2f(sacc[nt][r] - mnew);
                p[nt][r] = pv;
                ps += pv;
            }
        ps += __shfl_xor(ps, 16);
        ps += __shfl_xor(ps, 32);
        lrow = lrow * corr + ps;

        // pack P -> LDS: lane writes row q=lc, cols nt*16+g*4..+3 (b64, swizzled)
        #pragma unroll
        for (int nt = 0; nt < 4; ++nt) {
            const u32 a0 = __builtin_bit_cast(u32, p[nt][0]);
            const u32 a1 = __builtin_bit_cast(u32, p[nt][1]);
            const u32 a2 = __builtin_bit_cast(u32, p[nt][2]);
            const u32 a3 = __builtin_bit_cast(u32, p[nt][3]);
            uint2 pk;
            pk.x = ((a0 + 0x8000u) >> 16) | ((a1 + 0x8000u) & 0xFFFF0000u);
            pk.y = ((a2 + 0x8000u) >> 16) | ((a3 + 0x8000u) & 0xFFFF0000u);
            *(uint2*)&Pw[lc * 64 + ((nt * 16 + g * 4) ^ hsw)] = pk;
        }

        // rescale O (oacc[nt][r] is q = g*4+r, d = nt*16+lc): broadcast corr
        float cq[4];
        #pragma unroll
        for (int r = 0; r < 4; ++r) cq[r] = __shfl(corr, g * 4 + r);
        #pragma unroll
        for (int nt = 0; nt < 4; ++nt)
            #pragma unroll
            for (int r = 0; r < 4; ++r) oacc[nt][r] *= cq[r];

        // O += P @ V  (P: swizzled b128 reads; V^T: swizzled b128 reads)
        __builtin_amdgcn_s_setprio(1);
        #pragma unroll
        for (int kk = 0; kk < 2; ++kk) {
            const bf16x8 pa = *(const bf16x8*)
                &Pw[lc * 64 + ((kk * 32 + g * 8) ^ hsw)];
            #pragma unroll
            for (int nt = 0; nt < 4; ++nt) {
                const int vrow = nt * 16 + lc;          // = d
                const bf16x8 vb = *(const bf16x8*)
                    &Vts[vrow * 64 + (((kk * 4 + g) ^ (lc & 7)) * 8)];
                oacc[nt] = MFMA_BF16(pa, vb, oacc[nt]);
            }
        }
        __builtin_amdgcn_s_setprio(0);
    }

    // epilogue: normalize (lrow lives at lane q; broadcast), store
    float lq[4];
    #pragma unroll
    for (int r = 0; r < 4; ++r) lq[r] = 1.0f / __shfl(lrow, g * 4 + r);
    #pragma unroll
    for (int nt = 0; nt < 4; ++nt)
        #pragma unroll
        for (int r = 0; r < 4; ++r) {
            const float o = oacc[nt][r] * lq[r];
            const size_t token = tok0 + qt * 64 + w * 16 + g * 4 + r;
            ctx[token * 1024 + h * 64 + nt * 16 + lc] = f2bf(o);
        }
}

// -----------------------------------------------------------------------------
extern "C" void kernel_launch(void* const* d_in, const int* in_sizes, int n_in,
                              void* d_out, int out_size, void* d_ws, size_t ws_size,
                              hipStream_t stream) {
    const float* x      = (const float*)d_in[0];
    const float* qkv_w  = (const float*)d_in[1];
    const float* out_w  = (const float*)d_in[2];
    const float* up_w   = (const float*)d_in[3];
    const float* down_w = (const float*)d_in[4];
    const float* n1s    = (const float*)d_in[5];
    const float* n1b    = (const float*)d_in[6];
    const float* n2s    = (const float*)d_in[7];
    const float* n2b    = (const float*)d_in[8];
    float* out = (float*)d_out;

    char* ws = (char*)d_ws;
    size_t off = 0;
    auto alloc = [&](size_t bytes) -> void* {
        void* p = ws + off;
        off += (bytes + 255) & ~(size_t)255;
        return p;
    };
    u16*   qkvw_b = (u16*)alloc(3072ull * 1024 * 2);
    u16*   outw_b = (u16*)alloc(1024ull * 1024 * 2);
    u16*   upw_b  = (u16*)alloc(4096ull * 1024 * 2);
    u16*   dnw_b  = (u16*)alloc(1024ull * 4096 * 2);
    u16*   h_b    = (u16*)alloc(4096ull * 1024 * 2);
    u16*   qkv_o  = (u16*)alloc(4096ull * 3072 * 2);
    u16*   ctx    = (u16*)alloc(4096ull * 1024 * 2);
    float* x2     = (float*)alloc(4096ull * 1024 * 4);
    u16*   u      = (u16*)alloc(4096ull * 4096 * 2);
    // vt aliases u: vt live [tr_v_k .. attn_k]; u live [ffn-up .. ffn-down].
    u16*   vt     = u;

    hipFuncSetAttribute((const void*)&gemm256_k<32, 0>,
                        hipFuncAttributeMaxDynamicSharedMemorySize, 131072);
    hipFuncSetAttribute((const void*)&gemm256_k<32, 2>,
                        hipFuncAttributeMaxDynamicSharedMemorySize, 131072);
    hipFuncSetAttribute((const void*)&gemm128p_k<32, 1>,
                        hipFuncAttributeMaxDynamicSharedMemorySize, 65536);
    hipFuncSetAttribute((const void*)&gemm128p_k<128, 1>,
                        hipFuncAttributeMaxDynamicSharedMemorySize, 65536);

    // weight conversions
    cvt_k<<<(3072 * 1024 / 4 + 255) / 256, 256, 0, stream>>>(qkv_w,  qkvw_b, 3072 * 1024 / 4);
    cvt_k<<<(1024 * 1024 / 4 + 255) / 256, 256, 0, stream>>>(out_w,  outw_b, 1024 * 1024 / 4);
    cvt_k<<<(4096 * 1024 / 4 + 255) / 256, 256, 0, stream>>>(up_w,   upw_b,  4096 * 1024 / 4);
    cvt_k<<<(1024 * 4096 / 4 + 255) / 256, 256, 0, stream>>>(down_w, dnw_b,  1024 * 4096 / 4);

    // --- attention sublayer ---
    ln_k<<<4096, 256, 0, stream>>>(x, h_b, n1s, n1b);
    gemm256_k<32, 0><<<dim3(12, 16), 512, 131072, stream>>>(h_b, qkvw_b, qkv_o,
                                                            nullptr, nullptr,
                                                            4096, 3072, 1024);
    tr_v_k<<<dim3(32, 32), 256, 0, stream>>>(qkv_o, vt);
    attn_k<<<dim3(32, 32), 256, 0, stream>>>(qkv_o, vt, ctx);
    gemm128p_k<32, 1><<<dim3(8, 32), 256, 65536, stream>>>(ctx, outw_b, nullptr, x2, x,
                                                           4096, 1024, 1024);

    // --- FFN sublayer ---
    ln_k<<<4096, 256, 0, stream>>>(x2, h_b, n2s, n2b);
    gemm256_k<32, 2><<<dim3(16, 16), 512, 131072, stream>>>(h_b, upw_b, u,
                                                            nullptr, nullptr,
                                                            4096, 4096, 1024);
    gemm128p_k<128, 1><<<dim3(8, 32), 256, 65536, stream>>>(u, dnw_b, nullptr, out, x2,
                                                            4096, 1024, 4096);
}

// Round 6
// 254.335 us; speedup vs baseline: 1.8933x; 1.0721x over previous
//
#include <hip/hip_runtime.h>

typedef unsigned short u16;
typedef unsigned int u32;
typedef __attribute__((ext_vector_type(8))) short bf16x8;
typedef __attribute__((ext_vector_type(4))) float f32x4;

#define MFMA_BF16(a, b, c) __builtin_amdgcn_mfma_f32_16x16x32_bf16((a), (b), (c), 0, 0, 0)
#define BAR() __builtin_amdgcn_s_barrier()
#define WAITV(n) asm volatile("s_waitcnt vmcnt(" #n ")" ::: "memory")

__device__ __forceinline__ u16 f2bf(float f) {
    u32 u = __builtin_bit_cast(u32, f);
    u32 r = u + 0x7FFFu + ((u >> 16) & 1u);   // round-to-nearest-even
    return (u16)(r >> 16);
}

__device__ __forceinline__ void gld16(const void* g, void* s) {
    __builtin_amdgcn_global_load_lds(
        (const __attribute__((address_space(1))) unsigned int*)g,
        (__attribute__((address_space(3))) unsigned int*)s, 16, 0, 0);
}

// ---------------- f32 -> bf16 convert (weights) ----------------
__global__ void cvt_k(const float* __restrict__ in, u16* __restrict__ out, int n4) {
    int i = blockIdx.x * blockDim.x + threadIdx.x;
    if (i >= n4) return;
    float4 v = ((const float4*)in)[i];
    ushort4 o;
    o.x = f2bf(v.x); o.y = f2bf(v.y); o.z = f2bf(v.z); o.w = f2bf(v.w);
    ((ushort4*)out)[i] = o;
}

// ---------------- LayerNorm (1024 cols) -> bf16 ----------------
__global__ __launch_bounds__(256) void ln_k(const float* __restrict__ x,
                                            u16* __restrict__ out,
                                            const float* __restrict__ sc,
                                            const float* __restrict__ bi) {
    const int row = blockIdx.x;
    const int tid = threadIdx.x;
    const float4 v = ((const float4*)(x + (size_t)row * 1024))[tid];
    float s  = v.x + v.y + v.z + v.w;
    float s2 = v.x*v.x + v.y*v.y + v.z*v.z + v.w*v.w;
    #pragma unroll
    for (int m = 32; m; m >>= 1) { s += __shfl_xor(s, m); s2 += __shfl_xor(s2, m); }
    __shared__ float red[8];
    const int w = tid >> 6, l = tid & 63;
    if (l == 0) { red[w] = s; red[4 + w] = s2; }
    __syncthreads();
    s  = red[0] + red[1] + red[2] + red[3];
    s2 = red[4] + red[5] + red[6] + red[7];
    const float mu  = s * (1.0f / 1024.0f);
    const float var = s2 * (1.0f / 1024.0f) - mu * mu;
    const float rs  = rsqrtf(var + 1e-5f);
    const float4 sv = ((const float4*)sc)[tid];
    const float4 bv = ((const float4*)bi)[tid];
    ushort4 o;
    o.x = f2bf((v.x - mu) * rs * sv.x + bv.x);
    o.y = f2bf((v.y - mu) * rs * sv.y + bv.y);
    o.z = f2bf((v.z - mu) * rs * sv.z + bv.z);
    o.w = f2bf((v.w - mu) * rs * sv.w + bv.w);
    ((ushort4*)(out + (size_t)row * 1024))[tid] = o;
}

// ---------------- 256^2-tile GEMM, BK=64, 2-slot ring, 4-phase ---------------
// 8 waves (2Mx4N), per-wave 128x64 out. LDS = 2 slots x 64 KiB (A[256][64] +
// B[256][64] bf16, 128 B rows, octet swizzle ^= row&7 via pre-swizzled src).
// STAGE(t+1) split into 4 chunks: chunk0 at tile top BEFORE vmcnt(2) (2 loads
// stay in flight across the barrier), chunks 1-3 one per phase. Ring safety:
// chunk0 writes rows 0-63 of slot (t+1)&1; previous tile's last-phase reads
// are A-rows >=96 of the same slot -- disjoint. Everything else ordered by
// the tile-top WAITV+BAR.
// EPI 0: bf16 store, cols<1024 scaled by 0.125*log2e (pre-scales Q for attn).
// EPI 2: exact gelu -> bf16.
template<int NT, int EPI>
__global__ __launch_bounds__(512, 1) void gemm256_k(const u16* __restrict__ A,
                                                    const u16* __restrict__ B,
                                                    u16* __restrict__ Cb,
                                                    float* __restrict__ Cf,
                                                    const float* __restrict__ resid,
                                                    int M, int N, int K) {
    extern __shared__ u16 L[];          // 2 slots x 32768 u16
    const int tid = threadIdx.x;
    const int w = tid >> 6, l = tid & 63, g = l >> 4, lc = l & 15;
    const int wr = w >> 2, wc = w & 3;
    const int row0 = blockIdx.y * 256, col0 = blockIdx.x * 256;

    const u16* gA = A + (size_t)row0 * K;
    const u16* gB = B + (size_t)col0 * K;
    int srow[4], soct[4];
    #pragma unroll
    for (int p = 0; p < 4; ++p) {
        const int idx = p * 512 + tid;
        srow[p] = idx >> 3;
        soct[p] = (idx & 7) ^ (srow[p] & 7);
    }

#define STG(t, p) do { \
        char* base_ = (char*)L + ((t) & 1) * 65536; \
        gld16(gA + (size_t)srow[p] * K + (size_t)(t) * 64 + soct[p] * 8, \
              base_ + ((p) * 512 + tid) * 16); \
        gld16(gB + (size_t)srow[p] * K + (size_t)(t) * 64 + soct[p] * 8, \
              base_ + 32768 + ((p) * 512 + tid) * 16); \
    } while (0)

    f32x4 acc[8][4] = {};

    STG(0, 0); STG(0, 1); STG(0, 2); STG(0, 3);

    const int ocx = lc & 7;

    for (int t = 0; t < NT; ++t) {
        const bool pf = (t + 1 < NT);
        if (pf) { STG(t + 1, 0); WAITV(2); } else { WAITV(0); }
        BAR();

        const u16* La = L + (t & 1) * 32768;
        const u16* Lb = La + 16384;

        bf16x8 bfr[4][2];
        #pragma unroll
        for (int j = 0; j < 4; ++j)
            #pragma unroll
            for (int kk = 0; kk < 2; ++kk)
                bfr[j][kk] = *(const bf16x8*)
                    &Lb[(wc * 64 + j * 16 + lc) * 64 + (((kk * 4 + g) ^ ocx) * 8)];

        #pragma unroll
        for (int ph = 0; ph < 4; ++ph) {
            if (ph) {
                if (pf) STG(t + 1, ph);
                BAR();
            }
            bf16x8 af[2][2];
            #pragma unroll
            for (int ii = 0; ii < 2; ++ii)
                #pragma unroll
                for (int kk = 0; kk < 2; ++kk)
                    af[ii][kk] = *(const bf16x8*)
                        &La[(wr * 128 + (ph * 2 + ii) * 16 + lc) * 64 +
                            (((kk * 4 + g) ^ ocx) * 8)];
            __builtin_amdgcn_s_setprio(1);
            #pragma unroll
            for (int ii = 0; ii < 2; ++ii)
                #pragma unroll
                for (int j = 0; j < 4; ++j)
                    #pragma unroll
                    for (int kk = 0; kk < 2; ++kk)
                        acc[ph * 2 + ii][j] = MFMA_BF16(af[ii][kk], bfr[j][kk],
                                                        acc[ph * 2 + ii][j]);
            __builtin_amdgcn_s_setprio(0);
        }
    }
#undef STG

    #pragma unroll
    for (int i = 0; i < 8; ++i)
        #pragma unroll
        for (int j = 0; j < 4; ++j)
            #pragma unroll
            for (int r = 0; r < 4; ++r) {
                const int row = row0 + wr * 128 + i * 16 + g * 4 + r;
                const int col = col0 + wc * 64 + j * 16 + lc;
                const size_t off = (size_t)row * N + col;
                const float v = acc[i][j][r];
                if (EPI == 0) {
                    const float vv = (col < 1024) ? v * 0.180336880f : v;
                    Cb[off] = f2bf(vv);
                } else if (EPI == 1) {
                    Cf[off] = v + resid[off];
                } else {
                    const float gv = 0.5f * v * (1.0f + erff(v * 0.70710678118f));
                    Cb[off] = f2bf(gv);
                }
            }
}

// ---------------- 128^2-tile deep-pipelined GEMM (counted vmcnt) -------------
// 4 waves (2x2), BK=32, 4-slot ring (64 KiB), prefetch distance 3, vmcnt(10).
template<int NT, int EPI>
__global__ __launch_bounds__(256) void gemm128p_k(const u16* __restrict__ A,
                                                  const u16* __restrict__ B,
                                                  u16* __restrict__ Cb,
                                                  float* __restrict__ Cf,
                                                  const float* __restrict__ resid,
                                                  int M, int N, int K) {
    extern __shared__ u16 L[];          // 4 slots x (A 8192B + B 8192B)
    const int tid = threadIdx.x;
    const int w = tid >> 6, l = tid & 63, g = l >> 4, lc = l & 15;
    const int wr = w >> 1, wc = w & 1;
    const int row0 = blockIdx.y * 128, col0 = blockIdx.x * 128;

    const int sr = tid >> 2;
    const int qs = (tid & 3) ^ (sr & 3);
    const u16* ga = A + (size_t)(row0 + sr) * K + qs * 8;
    const u16* gb = B + (size_t)(col0 + sr) * K + qs * 8;

#define PSTAGE_A(t) do { \
        char* d_ = (char*)&L[((t) & 3) * 8192]; \
        gld16(ga + (size_t)(t) * 32,                d_ + tid * 16); \
        gld16(ga + (size_t)64 * K + (size_t)(t) * 32, d_ + tid * 16 + 4096); \
    } while (0)
#define PSTAGE_B(t) do { \
        char* d_ = (char*)&L[((t) & 3) * 8192] + 8192; \
        gld16(gb + (size_t)(t) * 32,                d_ + tid * 16); \
        gld16(gb + (size_t)64 * K + (size_t)(t) * 32, d_ + tid * 16 + 4096); \
    } while (0)

    f32x4 acc[4][4] = {};

    PSTAGE_A(0); PSTAGE_B(0);
    PSTAGE_A(1); PSTAGE_B(1);
    PSTAGE_A(2); PSTAGE_B(2);

    const int oc = (g ^ (lc & 3)) * 8;

    for (int t = 0; t < NT; ++t) {
        if (t + 3 < NT) PSTAGE_A(t + 3);
        if      (t < NT - 3) WAITV(10);
        else if (t == NT - 3) WAITV(8);
        else if (t == NT - 2) WAITV(4);
        else                  WAITV(0);
        BAR();

        const u16* Ls = &L[(t & 3) * 8192];
        bf16x8 af[4], bfr[4];
        #pragma unroll
        for (int i = 0; i < 4; ++i)
            af[i] = *(const bf16x8*)&Ls[(wr * 64 + i * 16 + lc) * 32 + oc];
        #pragma unroll
        for (int j = 0; j < 4; ++j)
            bfr[j] = *(const bf16x8*)&Ls[4096 + (wc * 64 + j * 16 + lc) * 32 + oc];

        if (t + 3 < NT) PSTAGE_B(t + 3);

        __builtin_amdgcn_s_setprio(1);
        #pragma unroll
        for (int i = 0; i < 4; ++i)
            #pragma unroll
            for (int j = 0; j < 4; ++j)
                acc[i][j] = MFMA_BF16(af[i], bfr[j], acc[i][j]);
        __builtin_amdgcn_s_setprio(0);
        BAR();
    }
#undef PSTAGE_A
#undef PSTAGE_B

    #pragma unroll
    for (int i = 0; i < 4; ++i)
        #pragma unroll
        for (int j = 0; j < 4; ++j)
            #pragma unroll
            for (int r = 0; r < 4; ++r) {
                const int row = row0 + wr * 64 + i * 16 + g * 4 + r;
                const int col = col0 + wc * 64 + j * 16 + lc;
                const size_t off = (size_t)row * N + col;
                const float v = acc[i][j][r];
                if (EPI == 0) {
                    Cb[off] = f2bf(v);
                } else if (EPI == 1) {
                    Cf[off] = v + resid[off];
                } else {
                    const float gv = 0.5f * v * (1.0f + erff(v * 0.70710678118f));
                    Cb[off] = f2bf(gv);
                }
            }
}

// ---------------- V transpose: qkv V-part [token][h*64+d] -> vt[bh][d][token] --
__global__ __launch_bounds__(256) void tr_v_k(const u16* __restrict__ qkv,
                                              u16* __restrict__ vt) {
    const int tt = blockIdx.x;          // token tile 0..31
    const int bh = blockIdx.y;          // 0..31
    const int b = bh >> 4, h = bh & 15;
    const u16* src = qkv + (size_t)(b * 2048 + tt * 64) * 3072 + 2048 + h * 64;
    u16* dst = vt + (size_t)bh * 64 * 2048 + tt * 64;

    __shared__ u16 T[64 * 64];          // swizzled: V[row][d] at row*64 + ((d>>3)^(row&7))*8 + (d&7)

    #pragma unroll
    for (int it = 0; it < 2; ++it) {
        const int idx = it * 256 + threadIdx.x;
        const int trow = idx >> 3, oct = idx & 7;
        const uint4 v = *(const uint4*)(src + (size_t)trow * 3072 + oct * 8);
        *(uint4*)&T[trow * 64 + ((oct ^ (trow & 7)) * 8)] = v;
    }
    __syncthreads();
    #pragma unroll
    for (int it = 0; it < 2; ++it) {
        const int idx = it * 256 + threadIdx.x;
        const int d = idx >> 3, t8 = idx & 7;
        ushort vals[8];
        #pragma unroll
        for (int j = 0; j < 8; ++j) {
            const int row = t8 * 8 + j;
            vals[j] = T[row * 64 + (((d >> 3) ^ (row & 7)) * 8) + (d & 7)];
        }
        *(uint4*)(dst + (size_t)d * 2048 + t8 * 8) = *(const uint4*)vals;
    }
}

// ---------------- Flash attention: B=2, H=16, S=2048, D=64 -------------------
// Swapped QK^T (lane holds 16 P values for one q=lc); in-lane softmax with
// defer-max (THR=8 in log2 domain); P packed via v_cvt_pk_bf16_f32; staging
// pointers hoisted out of the K-loop. Q pre-scaled by 0.125*log2e upstream.
__global__ __launch_bounds__(256) void attn_k(const u16* __restrict__ qkv,
                                              const u16* __restrict__ vt,
                                              u16* __restrict__ ctx) {
    const int qt = blockIdx.x;          // 0..31  (q tile of 64 rows)
    const int bh = blockIdx.y;          // 0..31
    const int b = bh >> 4, h = bh & 15;
    const int tid = threadIdx.x, w = tid >> 6, l = tid & 63, g = l >> 4, lc = l & 15;
    const size_t tok0 = (size_t)b * 2048;

    const u16* Qg  = qkv + (tok0 + qt * 64) * 3072 + h * 64;
    const u16* Kg  = qkv + tok0 * 3072 + 1024 + h * 64;
    const u16* Vtg = vt + (size_t)bh * 64 * 2048;      // [d][token-in-batch]

    __shared__ u16 Ks[64 * 64];
    __shared__ u16 Vts[64 * 64];        // [d][key] swizzled like Ks
    __shared__ u16 QPs[64 * 64];        // Q tile in prologue, then P strips (1024 u16/wave)
    u16* Pw = QPs + w * 1024;

    // hoisted staging geometry (constant across K-tiles)
    const int s0r = tid >> 3,        s0c = (tid & 7) ^ (s0r & 7);
    const int s1r = (tid + 256) >> 3, s1c = ((tid + 256) & 7) ^ (s1r & 7);

    // stage Q tile (swizzled source, linear dest)
    gld16(Qg + (size_t)s0r * 3072 + s0c * 8, (char*)QPs + tid * 16);
    gld16(Qg + (size_t)s1r * 3072 + s1c * 8, (char*)QPs + (tid + 256) * 16);
    __syncthreads();
    bf16x8 qf[2];
    {
        const int qrow = w * 16 + lc;
        qf[0] = *(const bf16x8*)&QPs[qrow * 64 + ((g       ^ (lc & 7)) * 8)];
        qf[1] = *(const bf16x8*)&QPs[qrow * 64 + (((4 + g) ^ (lc & 7)) * 8)];
    }

    const u16* kp0 = Kg + (size_t)s0r * 3072 + s0c * 8;
    const u16* kp1 = Kg + (size_t)s1r * 3072 + s1c * 8;
    const u16* vp0 = Vtg + (size_t)s0r * 2048 + s0c * 8;
    const u16* vp1 = Vtg + (size_t)s1r * 2048 + s1c * 8;

    f32x4 oacc[4] = {};
    float mrow = -1e30f, lrow = 0.0f;   // per-lane: q = lc
    const int hsw = (lc & 7) << 3;      // P row swizzle (u16 units, 16B granules)

    for (int kt = 0; kt < 32; ++kt) {
        __syncthreads();
        gld16(kp0, (char*)Ks + tid * 16);
        gld16(vp0, (char*)Vts + tid * 16);
        gld16(kp1, (char*)Ks + (tid + 256) * 16);
        gld16(vp1, (char*)Vts + (tid + 256) * 16);
        kp0 += 64 * 3072; kp1 += 64 * 3072;
        vp0 += 64;        vp1 += 64;
        __syncthreads();

        // S^T strip: sacc[nt] holds S[key = nt*16+g*4+r][q = lc]
        f32x4 sacc[4] = {};
        __builtin_amdgcn_s_setprio(1);
        #pragma unroll
        for (int kk = 0; kk < 2; ++kk)
            #pragma unroll
            for (int nt = 0; nt < 4; ++nt) {
                const int krow = nt * 16 + lc;
                const bf16x8 kb = *(const bf16x8*)
                    &Ks[krow * 64 + (((kk * 4 + g) ^ (lc & 7)) * 8)];
                sacc[nt] = MFMA_BF16(kb, qf[kk], sacc[nt]);
            }
        __builtin_amdgcn_s_setprio(0);

        // online softmax (log2 domain) with defer-max, THR=8
        float mx = sacc[0][0];
        #pragma unroll
        for (int nt = 0; nt < 4; ++nt)
            #pragma unroll
            for (int r = 0; r < 4; ++r)
                mx = fmaxf(mx, sacc[nt][r]);
        mx = fmaxf(mx, __shfl_xor(mx, 16));
        mx = fmaxf(mx, __shfl_xor(mx, 32));
        const bool ru = __any(mx > mrow + 8.0f);
        float corr = 1.0f;
        if (ru) {
            const float mnew = fmaxf(mrow, mx);
            corr = exp2f(mrow - mnew);
            mrow = mnew;
        }

        float p[4][4];
        float ps = 0.0f;
        #pragma unroll
        for (int nt = 0; nt < 4; ++nt)
            #pragma unroll
            for (int r = 0; r < 4; ++r) {
                const float pv = exp2f(sacc[nt][r] - mrow);
                p[nt][r] = pv;
                ps += pv;
            }
        ps += __shfl_xor(ps, 16);
        ps += __shfl_xor(ps, 32);

        // pack P -> LDS: lane writes row q=lc, cols nt*16+g*4..+3 (b64, swizzled)
        #pragma unroll
        for (int nt = 0; nt < 4; ++nt) {
            uint2 pk;
            asm("v_cvt_pk_bf16_f32 %0, %1, %2" : "=v"(pk.x) : "v"(p[nt][0]), "v"(p[nt][1]));
            asm("v_cvt_pk_bf16_f32 %0, %1, %2" : "=v"(pk.y) : "v"(p[nt][2]), "v"(p[nt][3]));
            *(uint2*)&Pw[lc * 64 + ((nt * 16 + g * 4) ^ hsw)] = pk;
        }

        if (ru) {
            lrow = lrow * corr + ps;
            // rescale O (oacc[nt][r] is q=g*4+r, d=nt*16+lc): broadcast corr
            float cq[4];
            #pragma unroll
            for (int r = 0; r < 4; ++r) cq[r] = __shfl(corr, g * 4 + r);
            #pragma unroll
            for (int nt = 0; nt < 4; ++nt)
                #pragma unroll
                for (int r = 0; r < 4; ++r) oacc[nt][r] *= cq[r];
        } else {
            lrow += ps;
        }

        // O += P @ V  (P: swizzled b128 reads; V^T: swizzled b128 reads)
        __builtin_amdgcn_s_setprio(1);
        #pragma unroll
        for (int kk = 0; kk < 2; ++kk) {
            const bf16x8 pa = *(const bf16x8*)
                &Pw[lc * 64 + ((kk * 32 + g * 8) ^ hsw)];
            #pragma unroll
            for (int nt = 0; nt < 4; ++nt) {
                const int vrow = nt * 16 + lc;          // = d
                const bf16x8 vb = *(const bf16x8*)
                    &Vts[vrow * 64 + (((kk * 4 + g) ^ (lc & 7)) * 8)];
                oacc[nt] = MFMA_BF16(pa, vb, oacc[nt]);
            }
        }
        __builtin_amdgcn_s_setprio(0);
    }

    // epilogue: normalize (lrow lives at lane q; broadcast), store
    float lq[4];
    #pragma unroll
    for (int r = 0; r < 4; ++r) lq[r] = 1.0f / __shfl(lrow, g * 4 + r);
    #pragma unroll
    for (int nt = 0; nt < 4; ++nt)
        #pragma unroll
        for (int r = 0; r < 4; ++r) {
            const float o = oacc[nt][r] * lq[r];
            const size_t token = tok0 + qt * 64 + w * 16 + g * 4 + r;
            ctx[token * 1024 + h * 64 + nt * 16 + lc] = f2bf(o);
        }
}

// -----------------------------------------------------------------------------
extern "C" void kernel_launch(void* const* d_in, const int* in_sizes, int n_in,
                              void* d_out, int out_size, void* d_ws, size_t ws_size,
                              hipStream_t stream) {
    const float* x      = (const float*)d_in[0];
    const float* qkv_w  = (const float*)d_in[1];
    const float* out_w  = (const float*)d_in[2];
    const float* up_w   = (const float*)d_in[3];
    const float* down_w = (const float*)d_in[4];
    const float* n1s    = (const float*)d_in[5];
    const float* n1b    = (const float*)d_in[6];
    const float* n2s    = (const float*)d_in[7];
    const float* n2b    = (const float*)d_in[8];
    float* out = (float*)d_out;

    char* ws = (char*)d_ws;
    size_t off = 0;
    auto alloc = [&](size_t bytes) -> void* {
        void* p = ws + off;
        off += (bytes + 255) & ~(size_t)255;
        return p;
    };
    u16*   qkvw_b = (u16*)alloc(3072ull * 1024 * 2);
    u16*   outw_b = (u16*)alloc(1024ull * 1024 * 2);
    u16*   upw_b  = (u16*)alloc(4096ull * 1024 * 2);
    u16*   dnw_b  = (u16*)alloc(1024ull * 4096 * 2);
    u16*   h_b    = (u16*)alloc(4096ull * 1024 * 2);
    u16*   qkv_o  = (u16*)alloc(4096ull * 3072 * 2);
    u16*   ctx    = (u16*)alloc(4096ull * 1024 * 2);
    float* x2     = (float*)alloc(4096ull * 1024 * 4);
    u16*   u      = (u16*)alloc(4096ull * 4096 * 2);
    // vt aliases u: vt live [tr_v_k .. attn_k]; u live [ffn-up .. ffn-down].
    u16*   vt     = u;

    hipFuncSetAttribute((const void*)&gemm256_k<16, 0>,
                        hipFuncAttributeMaxDynamicSharedMemorySize, 131072);
    hipFuncSetAttribute((const void*)&gemm256_k<16, 2>,
                        hipFuncAttributeMaxDynamicSharedMemorySize, 131072);
    hipFuncSetAttribute((const void*)&gemm128p_k<32, 1>,
                        hipFuncAttributeMaxDynamicSharedMemorySize, 65536);
    hipFuncSetAttribute((const void*)&gemm128p_k<128, 1>,
                        hipFuncAttributeMaxDynamicSharedMemorySize, 65536);

    // weight conversions
    cvt_k<<<(3072 * 1024 / 4 + 255) / 256, 256, 0, stream>>>(qkv_w,  qkvw_b, 3072 * 1024 / 4);
    cvt_k<<<(1024 * 1024 / 4 + 255) / 256, 256, 0, stream>>>(out_w,  outw_b, 1024 * 1024 / 4);
    cvt_k<<<(4096 * 1024 / 4 + 255) / 256, 256, 0, stream>>>(up_w,   upw_b,  4096 * 1024 / 4);
    cvt_k<<<(1024 * 4096 / 4 + 255) / 256, 256, 0, stream>>>(down_w, dnw_b,  1024 * 4096 / 4);

    // --- attention sublayer ---
    ln_k<<<4096, 256, 0, stream>>>(x, h_b, n1s, n1b);
    gemm256_k<16, 0><<<dim3(12, 16), 512, 131072, stream>>>(h_b, qkvw_b, qkv_o,
                                                            nullptr, nullptr,
                                                            4096, 3072, 1024);
    tr_v_k<<<dim3(32, 32), 256, 0, stream>>>(qkv_o, vt);
    attn_k<<<dim3(32, 32), 256, 0, stream>>>(qkv_o, vt, ctx);
    gemm128p_k<32, 1><<<dim3(8, 32), 256, 65536, stream>>>(ctx, outw_b, nullptr, x2, x,
                                                           4096, 1024, 1024);

    // --- FFN sublayer ---
    ln_k<<<4096, 256, 0, stream>>>(x2, h_b, n2s, n2b);
    gemm256_k<16, 2><<<dim3(16, 16), 512, 131072, stream>>>(h_b, upw_b, u,
                                                            nullptr, nullptr,
                                                            4096, 4096, 1024);
    gemm128p_k<128, 1><<<dim3(8, 32), 256, 65536, stream>>>(u, dnw_b, nullptr, out, x2,
                                                            4096, 1024, 4096);
}